// Round 1
// 199.153 us; speedup vs baseline: 1.0389x; 1.0389x over previous
//
#include <hip/hip_runtime.h>

#define BB   4
#define SS   1024
#define DD   1024
#define HH   16
#define DHH  64
#define LN_EPS  (1e-3f)

typedef unsigned short u16;
typedef __attribute__((ext_vector_type(8))) short bf16x8;
typedef __attribute__((ext_vector_type(4))) float f32x4;

__device__ __forceinline__ u16 f2bf(float f) {
    union { float f; unsigned int u; } v; v.f = f;
    return (u16)((v.u + 0x7FFFu + ((v.u >> 16) & 1u)) >> 16);
}

// async global->LDS, 16B per lane; lane i lands at lds + i*16 (wave-uniform
// base, no per-lane scatter — swizzle is applied to the SOURCE address).
__device__ __forceinline__ void cp16(void* lds, const void* g) {
    __builtin_amdgcn_global_load_lds(
        (const __attribute__((address_space(1))) unsigned int*)g,
        (__attribute__((address_space(3))) unsigned int*)lds, 16, 0, 0);
}

// ---------------------------------------------------------------------------
// prep: z<3 -> fp32->bf16 convert of queries/keys/values into Abf[3][4096][1024]
//       z>=3 -> W[k][n] fp32 -> Wt[n][k] bf16 (transpose+convert)
// ---------------------------------------------------------------------------
__global__ __launch_bounds__(256) void prep(const float* __restrict__ q,
                                            const float* __restrict__ k,
                                            const float* __restrict__ v,
                                            const float* __restrict__ Wq,
                                            const float* __restrict__ Wk,
                                            const float* __restrict__ Wv,
                                            u16* __restrict__ Abf,
                                            u16* __restrict__ WtA) {
    __shared__ float Ts[64][65];
    const int z = blockIdx.z;
    const int tid = threadIdx.x;
    if (z < 3) {
        const float* src = (z == 0) ? q : (z == 1) ? k : v;
        u16* dst = Abf + (size_t)z * ((size_t)BB * SS * DD);
        const int N8 = BB * SS * DD / 8;
        for (int i = blockIdx.x * 256 + tid; i < N8; i += 256 * 256) {
            const float4 f0 = ((const float4*)src)[i * 2];
            const float4 f1 = ((const float4*)src)[i * 2 + 1];
            union { u16 u[8]; uint4 o; } t;
            t.u[0] = f2bf(f0.x); t.u[1] = f2bf(f0.y);
            t.u[2] = f2bf(f0.z); t.u[3] = f2bf(f0.w);
            t.u[4] = f2bf(f1.x); t.u[5] = f2bf(f1.y);
            t.u[6] = f2bf(f1.z); t.u[7] = f2bf(f1.w);
            ((uint4*)dst)[i] = t.o;
        }
    } else {
        const float* W = (z == 3) ? Wq : (z == 4) ? Wk : Wv;
        u16* Wt = WtA + (size_t)(z - 3) * DD * DD;
        const int k0 = (blockIdx.x >> 4) * 64, n0 = (blockIdx.x & 15) * 64;
        #pragma unroll
        for (int it = 0; it < 4; ++it) {
            const int idx = tid + it * 256;
            const int r = idx >> 4, c4 = (idx & 15) * 4;
            const float4 vv = *(const float4*)&W[(size_t)(k0 + r) * DD + n0 + c4];
            Ts[r][c4 + 0] = vv.x; Ts[r][c4 + 1] = vv.y;
            Ts[r][c4 + 2] = vv.z; Ts[r][c4 + 3] = vv.w;
        }
        __syncthreads();
        const int n = tid >> 2, kc = (tid & 3) * 16;
        #pragma unroll
        for (int p = 0; p < 8; ++p) {
            const unsigned int lo = f2bf(Ts[kc + p * 2 + 0][n]);
            const unsigned int hi = f2bf(Ts[kc + p * 2 + 1][n]);
            *(unsigned int*)&Wt[(size_t)(n0 + n) * DD + k0 + kc + p * 2] = lo | (hi << 16);
        }
    }
}

// ---------------------------------------------------------------------------
// Fused QKV projection GEMM — 256x256 tile, BK=64, 8 waves (2Mx4N), 512 thr.
// Counted-vmcnt pipeline (T3+T4), LDS split into 8 independent 16KB regions
// [buf][khalf][A|B]; tile t's k-half x is staged 3 sub-phases before use and
// its region's last reader drained a full sub-phase (with barrier) before the
// overwriting stage is issued. XOR chunk swizzle (T2) on source+read.
// Grid = 192 blocks (3z x 16m x 4n) -> one clean round on 256 CUs.
//   z=0: Q*0.125 [b][h][s][dh]; z=1: K; z=2: V^T [b][h][dh][s].
// ---------------------------------------------------------------------------
__global__ __launch_bounds__(512, 2) void gemm_fused(const u16* __restrict__ Abf,
                                                     const u16* __restrict__ WtA,
                                                     u16* __restrict__ Qbf,
                                                     u16* __restrict__ Kbf,
                                                     u16* __restrict__ Vtb) {
    __shared__ u16 lds[2][2][2][8192];   // [buf][khalf][A=0/B=1][256 rows x 32] = 128 KiB

    const int bid = blockIdx.x;
    const int swz = (bid & 7) * 24 + (bid >> 3);   // bijective, 192 % 8 == 0
    const int z   = swz >> 6;
    const int rem = swz & 63;
    const int m0  = (rem >> 2) * 256;
    const int n0  = (rem & 3) * 256;

    const u16* A  = Abf + (size_t)z * ((size_t)BB * SS * DD);
    const u16* Bm = WtA + (size_t)z * (DD * DD);

    const int tid  = threadIdx.x;
    const int wave = tid >> 6, lane = tid & 63;
    const int ln = lane & 15, quad = lane >> 4;
    const int wr = wave >> 2, wc = wave & 3;       // 2M x 4N wave grid

    // staging decomposition: LDS 16B-slot l = rd*512 + tid; row r = l>>2,
    // stored chunk cs = l&3 holds global chunk c = cs ^ ((r>>1)&3).
    int r_[2], c_[2];
    #pragma unroll
    for (int rd = 0; rd < 2; ++rd) {
        const int l = rd * 512 + tid;
        const int rr = l >> 2, cs = l & 3;
        r_[rd] = rr;
        c_[rd] = cs ^ ((rr >> 1) & 3);
    }
    const u16* srcA[2] = { A  + (size_t)(m0 + r_[0]) * DD + c_[0] * 8,
                           A  + (size_t)(m0 + r_[1]) * DD + c_[1] * 8 };
    const u16* srcB[2] = { Bm + (size_t)(n0 + r_[0]) * DD + c_[0] * 8,
                           Bm + (size_t)(n0 + r_[1]) * DD + c_[1] * 8 };

    // frag read offsets (u16 elements) within a 16KB region; chunk = quad,
    // swizzled the same way -> conflict-free ds_read_b128.
    int offA[8], offB[4];
    #pragma unroll
    for (int mi = 0; mi < 8; ++mi) {
        const int r = wr * 128 + mi * 16 + ln;
        offA[mi] = (r * 4 + (quad ^ ((r >> 1) & 3))) * 8;
    }
    #pragma unroll
    for (int nj = 0; nj < 4; ++nj) {
        const int r = wc * 64 + nj * 16 + ln;
        offB[nj] = (r * 4 + (quad ^ ((r >> 1) & 3))) * 8;
    }

    // one stage = tile T, k-half x: A half (2 cp16) + B half (2 cp16) = 4 vmem
    auto stage = [&](int T, int x) {
        const int cb = T & 1;
        const int koff = T * 64 + x * 32;
        #pragma unroll
        for (int rd = 0; rd < 2; ++rd) {
            cp16(&lds[cb][x][0][(rd * 512 + wave * 64) * 8], srcA[rd] + koff);
            cp16(&lds[cb][x][1][(rd * 512 + wave * 64) * 8], srcB[rd] + koff);
        }
    };

    f32x4 acc[8][4] = {};

    // prologue: t0.k0, t0.k1, t1.k0 in flight; wait oldest -> t0.k0 landed
    stage(0, 0); stage(0, 1); stage(1, 0);
    asm volatile("s_waitcnt vmcnt(8)" ::: "memory");
    __builtin_amdgcn_s_barrier();

    // issue schedule: (t,0) stages t+1.k1 ; (t,1) stages t+2.k0.
    // vmcnt at sub-phase s guarantees the region read at s+1 has landed
    // (per-wave count -> barrier makes it collective).
    #pragma unroll
    for (int t = 0; t < 16; ++t) {
        const int c = t & 1;
        #pragma unroll
        for (int x = 0; x < 2; ++x) {
            if (x == 0) { if (t < 15) stage(t + 1, 1); }
            else        { if (t < 14) stage(t + 2, 0); }

            bf16x8 af[8], bfv[4];
            const u16* Ar = &lds[c][x][0][0];
            const u16* Br = &lds[c][x][1][0];
            #pragma unroll
            for (int mi = 0; mi < 8; ++mi) af[mi] = *(const bf16x8*)&Ar[offA[mi]];
            #pragma unroll
            for (int nj = 0; nj < 4; ++nj) bfv[nj] = *(const bf16x8*)&Br[offB[nj]];

            if (x == 0) {
                if (t < 15) asm volatile("s_waitcnt vmcnt(8)" ::: "memory");
                else        asm volatile("s_waitcnt vmcnt(0)" ::: "memory");
            } else {
                if (t < 14)       asm volatile("s_waitcnt vmcnt(8)" ::: "memory");
                else if (t == 14) asm volatile("s_waitcnt vmcnt(4)" ::: "memory");
            }
            __builtin_amdgcn_s_barrier();

            __builtin_amdgcn_s_setprio(1);
            #pragma unroll
            for (int mi = 0; mi < 8; ++mi)
                #pragma unroll
                for (int nj = 0; nj < 4; ++nj)
                    acc[mi][nj] = __builtin_amdgcn_mfma_f32_16x16x32_bf16(
                        af[mi], bfv[nj], acc[mi][nj], 0, 0, 0);
            __builtin_amdgcn_s_setprio(0);
            __builtin_amdgcn_s_barrier();
        }
    }

    // epilogue — wave covers cols [n0+wc*64, +64) = exactly one head
    const int hh = (n0 >> 6) + wc;
    if (z < 2) {
        u16* C = (z == 0) ? Qbf : Kbf;
        const float scale = (z == 0) ? 0.125f : 1.0f;   // fold 1/sqrt(64) into Q
        #pragma unroll
        for (int mi = 0; mi < 8; ++mi) {
            const int mbase = m0 + wr * 128 + mi * 16 + quad * 4;
            const int bb = mbase >> 10, sb = mbase & 1023;
            #pragma unroll
            for (int nj = 0; nj < 4; ++nj) {
                const int dh = nj * 16 + ln;
                #pragma unroll
                for (int r = 0; r < 4; ++r)
                    C[(((size_t)bb * HH + hh) * SS + sb + r) * DHH + dh] =
                        f2bf(acc[mi][nj][r] * scale);
            }
        }
    } else {
        #pragma unroll
        for (int mi = 0; mi < 8; ++mi) {
            const int mbase = m0 + wr * 128 + mi * 16 + quad * 4;
            const int bb = mbase >> 10, sb = mbase & 1023;
            #pragma unroll
            for (int nj = 0; nj < 4; ++nj) {
                const int dh = nj * 16 + ln;
                uint2 pk;
                pk.x = (unsigned int)f2bf(acc[mi][nj][0]) | ((unsigned int)f2bf(acc[mi][nj][1]) << 16);
                pk.y = (unsigned int)f2bf(acc[mi][nj][2]) | ((unsigned int)f2bf(acc[mi][nj][3]) << 16);
                *(uint2*)&Vtb[(((size_t)bb * HH + hh) * DHH + dh) * SS + sb] = pk;
            }
        }
    }
}

// ---------------------------------------------------------------------------
// Flash attention, MFMA, no-max softmax. 64-key tiles (LDS 24.5 KB -> full
// 4 blocks/CU co-residency). Ps overlays the dead Q-staging buffer. XCD
// decode: xcd=bid&7 selects (b,h) residue -> each XCD reuses only 8 K/V
// pairs (2 MB, fits per-XCD L2).
// ---------------------------------------------------------------------------
__global__ __launch_bounds__(256) void attn_mfma(const u16* __restrict__ Qg,
                                                 const u16* __restrict__ Kg,
                                                 const u16* __restrict__ Vtg,
                                                 const int* __restrict__ qmask,
                                                 const int* __restrict__ kmask,
                                                 float* __restrict__ O) {
    __shared__ u16 QPs[64 * 68];   // Q stage (first 8KB, swizzled), then Ps pitch-68
    __shared__ u16 Ks[64 * 64];    // [key][dh] swizzled chunks, 8 KB
    __shared__ u16 Vs[64 * 64];    // [dh][key] swizzled chunks, 8 KB

    const int bid  = blockIdx.x;
    const int xcd  = bid & 7;
    const int rest = bid >> 3;           // 0..127
    const int bh   = (rest & 7) * 8 + xcd;   // 0..63
    const int qt   = rest >> 3;          // 0..15
    const int b    = bh >> 4, h = bh & 15;
    const int q0   = qt * 64;
    const int tid  = threadIdx.x;
    const int wave = tid >> 6, lane = tid & 63;
    const int ln = lane & 15, quad = lane >> 4;
    const size_t bhs = (size_t)b * HH + h;

    // stage Q (swizzled 8-chunk rows)
    #pragma unroll
    for (int w = 0; w < 2; ++w) {
        const int s = w * 256 + wave * 64 + lane;
        const int r = s >> 3, csrc = (s & 7) ^ (r & 7);
        cp16(&QPs[(size_t)(w * 256 + wave * 64) * 8],
             &Qg[(bhs * SS + q0 + r) * DHH + csrc * 8]);
    }
    __syncthreads();

    bf16x8 qf[2];
    #pragma unroll
    for (int kk = 0; kk < 2; ++kk) {
        const int r = wave * 16 + ln;
        qf[kk] = *(const bf16x8*)&QPs[((r << 3) + ((kk * 4 + quad) ^ (r & 7))) << 3];
    }

    f32x4 o[4] = {};
    float lsum[4] = {0.f, 0.f, 0.f, 0.f};
    const f32x4 zero = {0.f, 0.f, 0.f, 0.f};

    for (int kt = 0; kt < SS / 64; ++kt) {
        __syncthreads();   // prior tile's reads done before restage
        #pragma unroll
        for (int w = 0; w < 2; ++w) {
            const int s = w * 256 + wave * 64 + lane;
            const int r = s >> 3, csrc = (s & 7) ^ (r & 7);
            cp16(&Ks[(size_t)(w * 256 + wave * 64) * 8],
                 &Kg[(bhs * SS + kt * 64 + r) * DHH + csrc * 8]);
            cp16(&Vs[(size_t)(w * 256 + wave * 64) * 8],
                 &Vtg[(bhs * DHH + r) * SS + kt * 64 + csrc * 8]);
        }
        __syncthreads();

        // S = Q @ K^T (Q pre-scaled); p = mask * exp(s); spill to Ps
        #pragma unroll
        for (int nt = 0; nt < 4; ++nt) {
            const int krow = nt * 16 + ln;
            const bf16x8 k0f = *(const bf16x8*)&Ks[((krow << 3) + ((0 + quad) ^ (krow & 7))) << 3];
            const bf16x8 k1f = *(const bf16x8*)&Ks[((krow << 3) + ((4 + quad) ^ (krow & 7))) << 3];
            f32x4 sacc = __builtin_amdgcn_mfma_f32_16x16x32_bf16(qf[0], k0f, zero, 0, 0, 0);
            sacc = __builtin_amdgcn_mfma_f32_16x16x32_bf16(qf[1], k1f, sacc, 0, 0, 0);
            const int km = kmask[b * SS + kt * 64 + krow];
            #pragma unroll
            for (int r = 0; r < 4; ++r) {
                const float p = km ? __expf(sacc[r]) : 0.0f;
                lsum[r] += p;
                QPs[(wave * 16 + quad * 4 + r) * 68 + nt * 16 + ln] = f2bf(p);
            }
        }
        // Ps rows are wave-private; same-wave lgkm ordering covers the RAW.

        // O += P @ V
        #pragma unroll
        for (int kk2 = 0; kk2 < 2; ++kk2) {
            const bf16x8 pf = *(const bf16x8*)&QPs[(wave * 16 + ln) * 68 + kk2 * 32 + quad * 8];
            #pragma unroll
            for (int nt2 = 0; nt2 < 4; ++nt2) {
                const int vrow = nt2 * 16 + ln;
                const bf16x8 vf = *(const bf16x8*)&Vs[((vrow << 3) + ((kk2 * 4 + quad) ^ (vrow & 7))) << 3];
                o[nt2] = __builtin_amdgcn_mfma_f32_16x16x32_bf16(pf, vf, o[nt2], 0, 0, 0);
            }
        }
    }

    // epilogue: one cross-lane l-reduction, normalize, query mask, store
    #pragma unroll
    for (int r = 0; r < 4; ++r) {
        #pragma unroll
        for (int off = 1; off < 16; off <<= 1)
            lsum[r] += __shfl_xor(lsum[r], off);
        const int q = q0 + wave * 16 + quad * 4 + r;
        const float scale = (float)qmask[b * SS + q] / lsum[r];
        #pragma unroll
        for (int nt2 = 0; nt2 < 4; ++nt2)
            O[((size_t)b * SS + q) * DD + h * DHH + nt2 * 16 + ln] = o[nt2][r] * scale;
    }
}

// ---------------------------------------------------------------------------
// residual + LayerNorm over D=1024. One block (256 thr) per (b,s) row.
// ---------------------------------------------------------------------------
__global__ __launch_bounds__(256) void ln_kernel(const float* __restrict__ Qin,
                                                 const float* __restrict__ attn,
                                                 const float* __restrict__ gamma,
                                                 const float* __restrict__ beta,
                                                 float* __restrict__ out) {
    const int row = blockIdx.x;
    const int tid = threadIdx.x;
    const int wid = tid >> 6, lane = tid & 63;
    __shared__ float sred[4];

    const float4 qv = ((const float4*)Qin)[(size_t)row * 256 + tid];
    const float4 av = ((const float4*)attn)[(size_t)row * 256 + tid];
    float4 v;
    v.x = qv.x + av.x; v.y = qv.y + av.y;
    v.z = qv.z + av.z; v.w = qv.w + av.w;

    float sum = v.x + v.y + v.z + v.w;
    #pragma unroll
    for (int off = 32; off; off >>= 1) sum += __shfl_down(sum, off);
    if (lane == 0) sred[wid] = sum;
    __syncthreads();
    const float mean = (sred[0] + sred[1] + sred[2] + sred[3]) * (1.0f / DD);
    __syncthreads();

    const float dx = v.x - mean, dy = v.y - mean, dz = v.z - mean, dw = v.w - mean;
    float vs = dx * dx + dy * dy + dz * dz + dw * dw;
    #pragma unroll
    for (int off = 32; off; off >>= 1) vs += __shfl_down(vs, off);
    if (lane == 0) sred[wid] = vs;
    __syncthreads();
    const float var = (sred[0] + sred[1] + sred[2] + sred[3]) * (1.0f / DD);
    const float inv = rsqrtf(var + LN_EPS);

    const float4 g = ((const float4*)gamma)[tid];
    const float4 bt = ((const float4*)beta)[tid];
    float4 ov;
    ov.x = g.x * dx * inv + bt.x; ov.y = g.y * dy * inv + bt.y;
    ov.z = g.z * dz * inv + bt.z; ov.w = g.w * dw * inv + bt.w;
    ((float4*)out)[(size_t)row * 256 + tid] = ov;
}

// ---------------------------------------------------------------------------
extern "C" void kernel_launch(void* const* d_in, const int* in_sizes, int n_in,
                              void* d_out, int out_size, void* d_ws, size_t ws_size,
                              hipStream_t stream) {
    const float* queries = (const float*)d_in[0];
    const float* keys    = (const float*)d_in[1];
    const float* values  = (const float*)d_in[2];
    const int*   qmask   = (const int*)d_in[3];
    const int*   kmask   = (const int*)d_in[4];
    const float* Wq      = (const float*)d_in[5];
    const float* Wk      = (const float*)d_in[6];
    const float* Wv      = (const float*)d_in[7];
    const float* gamma   = (const float*)d_in[8];
    const float* beta    = (const float*)d_in[9];
    float* out = (float*)d_out;

    const size_t NTOK = (size_t)BB * SS;          // 4096
    // layout (54 MB): Abf[3] 24MB (Ob 16MB ALIASES it — gemm finishes reading
    // Abf before attn writes Ob; stream-ordered) | Qbf 8 | Kbf 8 | Vtb 8 | Wt 6
    u16* Abf = (u16*)d_ws;
    float* Ob = (float*)d_ws;
    u16* Qbf = Abf + 3 * NTOK * DD;
    u16* Kbf = Qbf + NTOK * DD;
    u16* Vtb = Kbf + NTOK * DD;
    u16* WtA = Vtb + NTOK * DD;

    prep<<<dim3(256, 1, 6), 256, 0, stream>>>(queries, keys, values, Wq, Wk, Wv, Abf, WtA);

    gemm_fused<<<192, 512, 0, stream>>>(Abf, WtA, Qbf, Kbf, Vtb);

    attn_mfma<<<BB * HH * (SS / 64), 256, 0, stream>>>(Qbf, Kbf, Vtb, qmask, kmask, Ob);

    ln_kernel<<<BB * SS, 256, 0, stream>>>(queries, Ob, gamma, beta, out);
}

// Round 2
// 198.952 us; speedup vs baseline: 1.0400x; 1.0010x over previous
//
#include <hip/hip_runtime.h>

#define BB   4
#define SS   1024
#define DD   1024
#define HH   16
#define DHH  64
#define LN_EPS  (1e-3f)

typedef unsigned short u16;
typedef __attribute__((ext_vector_type(8))) short bf16x8;
typedef __attribute__((ext_vector_type(4))) float f32x4;

__device__ __forceinline__ u16 f2bf(float f) {
    union { float f; unsigned int u; } v; v.f = f;
    return (u16)((v.u + 0x7FFFu + ((v.u >> 16) & 1u)) >> 16);
}

// pack two f32 -> two bf16 (RNE) in one VALU op
__device__ __forceinline__ unsigned int cvt_pk_bf16(float lo, float hi) {
    unsigned int r;
    asm("v_cvt_pk_bf16_f32 %0, %1, %2" : "=v"(r) : "v"(lo), "v"(hi));
    return r;
}

// async global->LDS, 16B per lane; lane i lands at lds + i*16 (wave-uniform
// base, no per-lane scatter — swizzle is applied to the SOURCE address).
__device__ __forceinline__ void cp16(void* lds, const void* g) {
    __builtin_amdgcn_global_load_lds(
        (const __attribute__((address_space(1))) unsigned int*)g,
        (__attribute__((address_space(3))) unsigned int*)lds, 16, 0, 0);
}

// ---------------------------------------------------------------------------
// prep: z<3 -> fp32->bf16 convert of queries/keys/values into Abf[3][4096][1024]
//       z>=3 -> W[k][n] fp32 -> Wt[n][k] bf16 (transpose+convert)
// ---------------------------------------------------------------------------
__global__ __launch_bounds__(256) void prep(const float* __restrict__ q,
                                            const float* __restrict__ k,
                                            const float* __restrict__ v,
                                            const float* __restrict__ Wq,
                                            const float* __restrict__ Wk,
                                            const float* __restrict__ Wv,
                                            u16* __restrict__ Abf,
                                            u16* __restrict__ WtA) {
    __shared__ float Ts[64][65];
    const int z = blockIdx.z;
    const int tid = threadIdx.x;
    if (z < 3) {
        const float* src = (z == 0) ? q : (z == 1) ? k : v;
        u16* dst = Abf + (size_t)z * ((size_t)BB * SS * DD);
        const int N8 = BB * SS * DD / 8;
        for (int i = blockIdx.x * 256 + tid; i < N8; i += 256 * 256) {
            const float4 f0 = ((const float4*)src)[i * 2];
            const float4 f1 = ((const float4*)src)[i * 2 + 1];
            union { u16 u[8]; uint4 o; } t;
            t.u[0] = f2bf(f0.x); t.u[1] = f2bf(f0.y);
            t.u[2] = f2bf(f0.z); t.u[3] = f2bf(f0.w);
            t.u[4] = f2bf(f1.x); t.u[5] = f2bf(f1.y);
            t.u[6] = f2bf(f1.z); t.u[7] = f2bf(f1.w);
            ((uint4*)dst)[i] = t.o;
        }
    } else {
        const float* W = (z == 3) ? Wq : (z == 4) ? Wk : Wv;
        u16* Wt = WtA + (size_t)(z - 3) * DD * DD;
        const int k0 = (blockIdx.x >> 4) * 64, n0 = (blockIdx.x & 15) * 64;
        #pragma unroll
        for (int it = 0; it < 4; ++it) {
            const int idx = tid + it * 256;
            const int r = idx >> 4, c4 = (idx & 15) * 4;
            const float4 vv = *(const float4*)&W[(size_t)(k0 + r) * DD + n0 + c4];
            Ts[r][c4 + 0] = vv.x; Ts[r][c4 + 1] = vv.y;
            Ts[r][c4 + 2] = vv.z; Ts[r][c4 + 3] = vv.w;
        }
        __syncthreads();
        const int n = tid >> 2, kc = (tid & 3) * 16;
        #pragma unroll
        for (int p = 0; p < 8; ++p) {
            const unsigned int lo = f2bf(Ts[kc + p * 2 + 0][n]);
            const unsigned int hi = f2bf(Ts[kc + p * 2 + 1][n]);
            *(unsigned int*)&Wt[(size_t)(n0 + n) * DD + k0 + kc + p * 2] = lo | (hi << 16);
        }
    }
}

// ---------------------------------------------------------------------------
// Fused QKV projection GEMM — 256x256 tile, BK=64, 8 waves (2Mx4N), 512 thr.
// Counted-vmcnt pipeline (T3+T4), LDS split into 8 independent 16KB regions.
// Grid = 192 blocks (3z x 16m x 4n) -> one clean round on 256 CUs.
//   z=0: Q*(0.125*log2e) [b][h][s][dh] (exp2-domain); z=1: K; z=2: V^T.
// ---------------------------------------------------------------------------
__global__ __launch_bounds__(512, 2) void gemm_fused(const u16* __restrict__ Abf,
                                                     const u16* __restrict__ WtA,
                                                     u16* __restrict__ Qbf,
                                                     u16* __restrict__ Kbf,
                                                     u16* __restrict__ Vtb) {
    __shared__ u16 lds[2][2][2][8192];   // [buf][khalf][A=0/B=1][256 rows x 32] = 128 KiB

    const int bid = blockIdx.x;
    const int swz = (bid & 7) * 24 + (bid >> 3);   // bijective, 192 % 8 == 0
    const int z   = swz >> 6;
    const int rem = swz & 63;
    const int m0  = (rem >> 2) * 256;
    const int n0  = (rem & 3) * 256;

    const u16* A  = Abf + (size_t)z * ((size_t)BB * SS * DD);
    const u16* Bm = WtA + (size_t)z * (DD * DD);

    const int tid  = threadIdx.x;
    const int wave = tid >> 6, lane = tid & 63;
    const int ln = lane & 15, quad = lane >> 4;
    const int wr = wave >> 2, wc = wave & 3;       // 2M x 4N wave grid

    int r_[2], c_[2];
    #pragma unroll
    for (int rd = 0; rd < 2; ++rd) {
        const int l = rd * 512 + tid;
        const int rr = l >> 2, cs = l & 3;
        r_[rd] = rr;
        c_[rd] = cs ^ ((rr >> 1) & 3);
    }
    const u16* srcA[2] = { A  + (size_t)(m0 + r_[0]) * DD + c_[0] * 8,
                           A  + (size_t)(m0 + r_[1]) * DD + c_[1] * 8 };
    const u16* srcB[2] = { Bm + (size_t)(n0 + r_[0]) * DD + c_[0] * 8,
                           Bm + (size_t)(n0 + r_[1]) * DD + c_[1] * 8 };

    int offA[8], offB[4];
    #pragma unroll
    for (int mi = 0; mi < 8; ++mi) {
        const int r = wr * 128 + mi * 16 + ln;
        offA[mi] = (r * 4 + (quad ^ ((r >> 1) & 3))) * 8;
    }
    #pragma unroll
    for (int nj = 0; nj < 4; ++nj) {
        const int r = wc * 64 + nj * 16 + ln;
        offB[nj] = (r * 4 + (quad ^ ((r >> 1) & 3))) * 8;
    }

    auto stage = [&](int T, int x) {
        const int cb = T & 1;
        const int koff = T * 64 + x * 32;
        #pragma unroll
        for (int rd = 0; rd < 2; ++rd) {
            cp16(&lds[cb][x][0][(rd * 512 + wave * 64) * 8], srcA[rd] + koff);
            cp16(&lds[cb][x][1][(rd * 512 + wave * 64) * 8], srcB[rd] + koff);
        }
    };

    f32x4 acc[8][4] = {};

    stage(0, 0); stage(0, 1); stage(1, 0);
    asm volatile("s_waitcnt vmcnt(8)" ::: "memory");
    __builtin_amdgcn_s_barrier();

    #pragma unroll
    for (int t = 0; t < 16; ++t) {
        const int c = t & 1;
        #pragma unroll
        for (int x = 0; x < 2; ++x) {
            if (x == 0) { if (t < 15) stage(t + 1, 1); }
            else        { if (t < 14) stage(t + 2, 0); }

            bf16x8 af[8], bfv[4];
            const u16* Ar = &lds[c][x][0][0];
            const u16* Br = &lds[c][x][1][0];
            #pragma unroll
            for (int mi = 0; mi < 8; ++mi) af[mi] = *(const bf16x8*)&Ar[offA[mi]];
            #pragma unroll
            for (int nj = 0; nj < 4; ++nj) bfv[nj] = *(const bf16x8*)&Br[offB[nj]];

            if (x == 0) {
                if (t < 15) asm volatile("s_waitcnt vmcnt(8)" ::: "memory");
                else        asm volatile("s_waitcnt vmcnt(0)" ::: "memory");
            } else {
                if (t < 14)       asm volatile("s_waitcnt vmcnt(8)" ::: "memory");
                else if (t == 14) asm volatile("s_waitcnt vmcnt(4)" ::: "memory");
            }
            __builtin_amdgcn_s_barrier();

            __builtin_amdgcn_s_setprio(1);
            #pragma unroll
            for (int mi = 0; mi < 8; ++mi)
                #pragma unroll
                for (int nj = 0; nj < 4; ++nj)
                    acc[mi][nj] = __builtin_amdgcn_mfma_f32_16x16x32_bf16(
                        af[mi], bfv[nj], acc[mi][nj], 0, 0, 0);
            __builtin_amdgcn_s_setprio(0);
            __builtin_amdgcn_s_barrier();
        }
    }

    const int hh = (n0 >> 6) + wc;
    if (z < 2) {
        u16* C = (z == 0) ? Qbf : Kbf;
        // z=0: fold 1/sqrt(64) AND log2(e) into Q so attn uses exp2 directly
        const float scale = (z == 0) ? 0.18033688f : 1.0f;
        #pragma unroll
        for (int mi = 0; mi < 8; ++mi) {
            const int mbase = m0 + wr * 128 + mi * 16 + quad * 4;
            const int bb = mbase >> 10, sb = mbase & 1023;
            #pragma unroll
            for (int nj = 0; nj < 4; ++nj) {
                const int dh = nj * 16 + ln;
                #pragma unroll
                for (int r = 0; r < 4; ++r)
                    C[(((size_t)bb * HH + hh) * SS + sb + r) * DHH + dh] =
                        f2bf(acc[mi][nj][r] * scale);
            }
        }
    } else {
        #pragma unroll
        for (int mi = 0; mi < 8; ++mi) {
            const int mbase = m0 + wr * 128 + mi * 16 + quad * 4;
            const int bb = mbase >> 10, sb = mbase & 1023;
            #pragma unroll
            for (int nj = 0; nj < 4; ++nj) {
                const int dh = nj * 16 + ln;
                uint2 pk;
                pk.x = cvt_pk_bf16(acc[mi][nj][0], acc[mi][nj][1]);
                pk.y = cvt_pk_bf16(acc[mi][nj][2], acc[mi][nj][3]);
                *(uint2*)&Vtb[(((size_t)bb * HH + hh) * DHH + dh) * SS + sb] = pk;
            }
        }
    }
}

// ---------------------------------------------------------------------------
// Flash attention, MFMA, no-max softmax. Pipelined: double-buffered K/V via
// counted vmcnt (never 0 mid-loop), raw s_barrier. Swapped QK^T (mfma(K,Q))
// => lane holds 4 address-consecutive P values -> cvt_pk_bf16 + ds_write_b64,
// lane-local l-sum. Q direct global->reg (fragment == 16B row read).
// kmask staged once to LDS as floats. LDS 44.5KB -> 3 blocks/CU.
// ---------------------------------------------------------------------------
__global__ __launch_bounds__(256) void attn_mfma(const u16* __restrict__ Qg,
                                                 const u16* __restrict__ Kg,
                                                 const u16* __restrict__ Vtg,
                                                 const int* __restrict__ qmask,
                                                 const int* __restrict__ kmask,
                                                 float* __restrict__ O) {
    __shared__ u16 Ps[64 * 68];          // P spill, pitch 68 (b64-aligned rows)
    __shared__ u16 Ks[2][64 * 64];       // [key][dh] swizzled chunks, dbuf
    __shared__ u16 Vs[2][64 * 64];       // [dh][key] swizzled chunks, dbuf
    __shared__ float kmLds[SS];          // key-mask as float 0/1

    const int bid  = blockIdx.x;
    const int xcd  = bid & 7;
    const int rest = bid >> 3;               // 0..127
    const int bh   = (rest & 7) * 8 + xcd;   // 0..63
    const int qt   = rest >> 3;              // 0..15
    const int b    = bh >> 4, h = bh & 15;
    const int q0   = qt * 64;
    const int tid  = threadIdx.x;
    const int wave = tid >> 6, lane = tid & 63;
    const int ln = lane & 15, quad = lane >> 4;
    const size_t bhs = (size_t)b * HH + h;

    auto stageKV = [&](int t) {
        const int cb = t & 1;
        #pragma unroll
        for (int w = 0; w < 2; ++w) {
            const int s = w * 256 + wave * 64 + lane;
            const int r = s >> 3, csrc = (s & 7) ^ (r & 7);
            cp16(&Ks[cb][(w * 256 + wave * 64) * 8],
                 &Kg[(bhs * SS + t * 64 + r) * DHH + csrc * 8]);
            cp16(&Vs[cb][(w * 256 + wave * 64) * 8],
                 &Vtg[(bhs * DHH + r) * SS + t * 64 + csrc * 8]);
        }
    };

    // --- prologue ---
    // Q fragment direct to registers: row q0+wave*16+ln, d = kk*32 + quad*8
    const u16* qrow = &Qg[(bhs * SS + q0 + wave * 16 + ln) * DHH];
    const bf16x8 qf0 = *(const bf16x8*)&qrow[quad * 8];
    const bf16x8 qf1 = *(const bf16x8*)&qrow[32 + quad * 8];
    asm volatile("" ::: "memory");       // pin qf issue before staging
    cp16(&kmLds[wave * 256], &kmask[b * SS + (wave * 64 + lane) * 4]);   // ints for now
    stageKV(0);
    stageKV(1);
    asm volatile("s_waitcnt vmcnt(4)" ::: "memory");   // qf+km+tile0 landed
    __builtin_amdgcn_s_barrier();

    // kmask int -> float in place (each thread owns its 4)
    {
        const int4 iv = *(const int4*)&kmLds[tid * 4];
        float4 fv;
        fv.x = (float)iv.x; fv.y = (float)iv.y;
        fv.z = (float)iv.z; fv.w = (float)iv.w;
        *(float4*)&kmLds[tid * 4] = fv;
    }
    asm volatile("s_waitcnt lgkmcnt(0)" ::: "memory");
    __builtin_amdgcn_s_barrier();

    f32x4 o[4] = {};
    float lsum = 0.f;
    const f32x4 zero = {0.f, 0.f, 0.f, 0.f};
    const int prow = (wave * 16 + ln) * 68;   // this lane's Ps row base

    #pragma unroll 2
    for (int kt = 0; kt < SS / 64; ++kt) {
        const int cb = kt & 1;
        const u16* Kc = Ks[cb];
        const u16* Vc = Vs[cb];

        // S^T = K @ Q^T (Q pre-scaled by 0.125*log2e); p = fm * exp2(s)
        // out: k-row = nt*16 + quad*4 + r, q-col = wave*16 + ln
        #pragma unroll
        for (int nt = 0; nt < 4; ++nt) {
            const int krow = nt * 16 + ln;
            const bf16x8 k0f = *(const bf16x8*)&Kc[((krow << 3) + ((0 + quad) ^ (krow & 7))) << 3];
            const bf16x8 k1f = *(const bf16x8*)&Kc[((krow << 3) + ((4 + quad) ^ (krow & 7))) << 3];
            f32x4 sacc = __builtin_amdgcn_mfma_f32_16x16x32_bf16(k0f, qf0, zero, 0, 0, 0);
            sacc = __builtin_amdgcn_mfma_f32_16x16x32_bf16(k1f, qf1, sacc, 0, 0, 0);
            const float4 fm = *(const float4*)&kmLds[kt * 64 + nt * 16 + quad * 4];
            const float p0 = fm.x * __builtin_amdgcn_exp2f(sacc[0]);
            const float p1 = fm.y * __builtin_amdgcn_exp2f(sacc[1]);
            const float p2 = fm.z * __builtin_amdgcn_exp2f(sacc[2]);
            const float p3 = fm.w * __builtin_amdgcn_exp2f(sacc[3]);
            lsum += (p0 + p1) + (p2 + p3);
            uint2 pk;
            pk.x = cvt_pk_bf16(p0, p1);
            pk.y = cvt_pk_bf16(p2, p3);
            *(uint2*)&Ps[prow + nt * 16 + quad * 4] = pk;   // 4 consecutive cols
        }
        // Ps rows are wave-private; same-wave lgkm ordering covers the RAW.

        // O += P @ V
        #pragma unroll
        for (int kk2 = 0; kk2 < 2; ++kk2) {
            const bf16x8 pf = *(const bf16x8*)&Ps[prow + kk2 * 32 + quad * 8];
            #pragma unroll
            for (int nt2 = 0; nt2 < 4; ++nt2) {
                const int vrow = nt2 * 16 + ln;
                const bf16x8 vf = *(const bf16x8*)&Vc[((vrow << 3) + ((kk2 * 4 + quad) ^ (vrow & 7))) << 3];
                o[nt2] = __builtin_amdgcn_mfma_f32_16x16x32_bf16(pf, vf, o[nt2], 0, 0, 0);
            }
        }

        if (kt == SS / 64 - 1) break;
        __builtin_amdgcn_s_barrier();        // all waves done reading buf cb
        if (kt + 2 < SS / 64) {
            stageKV(kt + 2);                 // overwrite buf cb
            asm volatile("s_waitcnt vmcnt(4)" ::: "memory");   // tile kt+1 landed
        } else {
            asm volatile("s_waitcnt vmcnt(0)" ::: "memory");   // last stage drain
        }
        __builtin_amdgcn_s_barrier();
    }

    // epilogue: quad-reduce lane-local l (q = wave*16+ln), normalize, store
    lsum += __shfl_xor(lsum, 16);
    lsum += __shfl_xor(lsum, 32);
    #pragma unroll
    for (int r = 0; r < 4; ++r) {
        const int qloc = quad * 4 + r;
        const float l = __shfl(lsum, qloc);        // lane qloc holds full sum
        const int q = q0 + wave * 16 + qloc;
        const float scale = (float)qmask[b * SS + q] / l;
        #pragma unroll
        for (int nt2 = 0; nt2 < 4; ++nt2)
            O[((size_t)b * SS + q) * DD + h * DHH + nt2 * 16 + ln] = o[nt2][r] * scale;
    }
}

// ---------------------------------------------------------------------------
// residual + LayerNorm over D=1024. One block (256 thr) per (b,s) row.
// ---------------------------------------------------------------------------
__global__ __launch_bounds__(256) void ln_kernel(const float* __restrict__ Qin,
                                                 const float* __restrict__ attn,
                                                 const float* __restrict__ gamma,
                                                 const float* __restrict__ beta,
                                                 float* __restrict__ out) {
    const int row = blockIdx.x;
    const int tid = threadIdx.x;
    const int wid = tid >> 6, lane = tid & 63;
    __shared__ float sred[4];

    const float4 qv = ((const float4*)Qin)[(size_t)row * 256 + tid];
    const float4 av = ((const float4*)attn)[(size_t)row * 256 + tid];
    float4 v;
    v.x = qv.x + av.x; v.y = qv.y + av.y;
    v.z = qv.z + av.z; v.w = qv.w + av.w;

    float sum = v.x + v.y + v.z + v.w;
    #pragma unroll
    for (int off = 32; off; off >>= 1) sum += __shfl_down(sum, off);
    if (lane == 0) sred[wid] = sum;
    __syncthreads();
    const float mean = (sred[0] + sred[1] + sred[2] + sred[3]) * (1.0f / DD);
    __syncthreads();

    const float dx = v.x - mean, dy = v.y - mean, dz = v.z - mean, dw = v.w - mean;
    float vs = dx * dx + dy * dy + dz * dz + dw * dw;
    #pragma unroll
    for (int off = 32; off; off >>= 1) vs += __shfl_down(vs, off);
    if (lane == 0) sred[wid] = vs;
    __syncthreads();
    const float var = (sred[0] + sred[1] + sred[2] + sred[3]) * (1.0f / DD);
    const float inv = rsqrtf(var + LN_EPS);

    const float4 g = ((const float4*)gamma)[tid];
    const float4 bt = ((const float4*)beta)[tid];
    float4 ov;
    ov.x = g.x * dx * inv + bt.x; ov.y = g.y * dy * inv + bt.y;
    ov.z = g.z * dz * inv + bt.z; ov.w = g.w * dw * inv + bt.w;
    ((float4*)out)[(size_t)row * 256 + tid] = ov;
}

// ---------------------------------------------------------------------------
extern "C" void kernel_launch(void* const* d_in, const int* in_sizes, int n_in,
                              void* d_out, int out_size, void* d_ws, size_t ws_size,
                              hipStream_t stream) {
    const float* queries = (const float*)d_in[0];
    const float* keys    = (const float*)d_in[1];
    const float* values  = (const float*)d_in[2];
    const int*   qmask   = (const int*)d_in[3];
    const int*   kmask   = (const int*)d_in[4];
    const float* Wq      = (const float*)d_in[5];
    const float* Wk      = (const float*)d_in[6];
    const float* Wv      = (const float*)d_in[7];
    const float* gamma   = (const float*)d_in[8];
    const float* beta    = (const float*)d_in[9];
    float* out = (float*)d_out;

    const size_t NTOK = (size_t)BB * SS;          // 4096
    // layout (54 MB): Abf[3] 24MB (Ob 16MB ALIASES it — gemm finishes reading
    // Abf before attn writes Ob; stream-ordered) | Qbf 8 | Kbf 8 | Vtb 8 | Wt 6
    u16* Abf = (u16*)d_ws;
    float* Ob = (float*)d_ws;
    u16* Qbf = Abf + 3 * NTOK * DD;
    u16* Kbf = Qbf + NTOK * DD;
    u16* Vtb = Kbf + NTOK * DD;
    u16* WtA = Vtb + NTOK * DD;

    prep<<<dim3(256, 1, 6), 256, 0, stream>>>(queries, keys, values, Wq, Wk, Wv, Abf, WtA);

    gemm_fused<<<192, 512, 0, stream>>>(Abf, WtA, Qbf, Kbf, Vtb);

    attn_mfma<<<BB * HH * (SS / 64), 256, 0, stream>>>(Qbf, Kbf, Vtb, qmask, kmask, Ob);

    ln_kernel<<<BB * SS, 256, 0, stream>>>(queries, Ob, gamma, beta, out);
}

// Round 3
// 186.855 us; speedup vs baseline: 1.1073x; 1.0647x over previous
//
#include <hip/hip_runtime.h>

#define BB   4
#define SS   1024
#define DD   1024
#define HH   16
#define DHH  64
#define LN_EPS  (1e-3f)

typedef unsigned short u16;
typedef __attribute__((ext_vector_type(8))) short bf16x8;
typedef __attribute__((ext_vector_type(4))) float f32x4;

__device__ __forceinline__ u16 f2bf(float f) {
    union { float f; unsigned int u; } v; v.f = f;
    return (u16)((v.u + 0x7FFFu + ((v.u >> 16) & 1u)) >> 16);
}

// pack two f32 -> two bf16 (RNE) in one VALU op
__device__ __forceinline__ unsigned int cvt_pk_bf16(float lo, float hi) {
    unsigned int r;
    asm("v_cvt_pk_bf16_f32 %0, %1, %2" : "=v"(r) : "v"(lo), "v"(hi));
    return r;
}

// async global->LDS, 16B per lane; lane i lands at lds + i*16 (wave-uniform
// base, no per-lane scatter — swizzle is applied to the SOURCE address).
__device__ __forceinline__ void cp16(void* lds, const void* g) {
    __builtin_amdgcn_global_load_lds(
        (const __attribute__((address_space(1))) unsigned int*)g,
        (__attribute__((address_space(3))) unsigned int*)lds, 16, 0, 0);
}

// ---------------------------------------------------------------------------
// prep: z<3 -> fp32->bf16 convert of queries/keys/values into Abf[3][4096][1024]
//       z>=3 -> W[k][n] fp32 -> Wt[n][k] bf16 (transpose+convert)
// ---------------------------------------------------------------------------
__global__ __launch_bounds__(256) void prep(const float* __restrict__ q,
                                            const float* __restrict__ k,
                                            const float* __restrict__ v,
                                            const float* __restrict__ Wq,
                                            const float* __restrict__ Wk,
                                            const float* __restrict__ Wv,
                                            u16* __restrict__ Abf,
                                            u16* __restrict__ WtA) {
    __shared__ float Ts[64][65];
    const int z = blockIdx.z;
    const int tid = threadIdx.x;
    if (z < 3) {
        const float* src = (z == 0) ? q : (z == 1) ? k : v;
        u16* dst = Abf + (size_t)z * ((size_t)BB * SS * DD);
        const int N8 = BB * SS * DD / 8;
        for (int i = blockIdx.x * 256 + tid; i < N8; i += 256 * 256) {
            const float4 f0 = ((const float4*)src)[i * 2];
            const float4 f1 = ((const float4*)src)[i * 2 + 1];
            union { u16 u[8]; uint4 o; } t;
            t.u[0] = f2bf(f0.x); t.u[1] = f2bf(f0.y);
            t.u[2] = f2bf(f0.z); t.u[3] = f2bf(f0.w);
            t.u[4] = f2bf(f1.x); t.u[5] = f2bf(f1.y);
            t.u[6] = f2bf(f1.z); t.u[7] = f2bf(f1.w);
            ((uint4*)dst)[i] = t.o;
        }
    } else {
        const float* W = (z == 3) ? Wq : (z == 4) ? Wk : Wv;
        u16* Wt = WtA + (size_t)(z - 3) * DD * DD;
        const int k0 = (blockIdx.x >> 4) * 64, n0 = (blockIdx.x & 15) * 64;
        #pragma unroll
        for (int it = 0; it < 4; ++it) {
            const int idx = tid + it * 256;
            const int r = idx >> 4, c4 = (idx & 15) * 4;
            const float4 vv = *(const float4*)&W[(size_t)(k0 + r) * DD + n0 + c4];
            Ts[r][c4 + 0] = vv.x; Ts[r][c4 + 1] = vv.y;
            Ts[r][c4 + 2] = vv.z; Ts[r][c4 + 3] = vv.w;
        }
        __syncthreads();
        const int n = tid >> 2, kc = (tid & 3) * 16;
        #pragma unroll
        for (int p = 0; p < 8; ++p) {
            const unsigned int lo = f2bf(Ts[kc + p * 2 + 0][n]);
            const unsigned int hi = f2bf(Ts[kc + p * 2 + 1][n]);
            *(unsigned int*)&Wt[(size_t)(n0 + n) * DD + k0 + kc + p * 2] = lo | (hi << 16);
        }
    }
}

// ---------------------------------------------------------------------------
// Fused QKV projection GEMM — 256x256 tile, BK=64, 8 waves (2Mx4N), 512 thr.
// Counted-vmcnt pipeline (T3+T4), LDS split into 8 independent 16KB regions.
// Grid = 192 blocks (3z x 16m x 4n) -> one clean round on 256 CUs.
//   z=0: Q*(0.125*log2e) [b][h][s][dh] (exp2-domain); z=1: K; z=2: V^T.
// ---------------------------------------------------------------------------
__global__ __launch_bounds__(512, 2) void gemm_fused(const u16* __restrict__ Abf,
                                                     const u16* __restrict__ WtA,
                                                     u16* __restrict__ Qbf,
                                                     u16* __restrict__ Kbf,
                                                     u16* __restrict__ Vtb) {
    __shared__ u16 lds[2][2][2][8192];   // [buf][khalf][A=0/B=1][256 rows x 32] = 128 KiB

    const int bid = blockIdx.x;
    const int swz = (bid & 7) * 24 + (bid >> 3);   // bijective, 192 % 8 == 0
    const int z   = swz >> 6;
    const int rem = swz & 63;
    const int m0  = (rem >> 2) * 256;
    const int n0  = (rem & 3) * 256;

    const u16* A  = Abf + (size_t)z * ((size_t)BB * SS * DD);
    const u16* Bm = WtA + (size_t)z * (DD * DD);

    const int tid  = threadIdx.x;
    const int wave = tid >> 6, lane = tid & 63;
    const int ln = lane & 15, quad = lane >> 4;
    const int wr = wave >> 2, wc = wave & 3;       // 2M x 4N wave grid

    int r_[2], c_[2];
    #pragma unroll
    for (int rd = 0; rd < 2; ++rd) {
        const int l = rd * 512 + tid;
        const int rr = l >> 2, cs = l & 3;
        r_[rd] = rr;
        c_[rd] = cs ^ ((rr >> 1) & 3);
    }
    const u16* srcA[2] = { A  + (size_t)(m0 + r_[0]) * DD + c_[0] * 8,
                           A  + (size_t)(m0 + r_[1]) * DD + c_[1] * 8 };
    const u16* srcB[2] = { Bm + (size_t)(n0 + r_[0]) * DD + c_[0] * 8,
                           Bm + (size_t)(n0 + r_[1]) * DD + c_[1] * 8 };

    int offA[8], offB[4];
    #pragma unroll
    for (int mi = 0; mi < 8; ++mi) {
        const int r = wr * 128 + mi * 16 + ln;
        offA[mi] = (r * 4 + (quad ^ ((r >> 1) & 3))) * 8;
    }
    #pragma unroll
    for (int nj = 0; nj < 4; ++nj) {
        const int r = wc * 64 + nj * 16 + ln;
        offB[nj] = (r * 4 + (quad ^ ((r >> 1) & 3))) * 8;
    }

    auto stage = [&](int T, int x) {
        const int cb = T & 1;
        const int koff = T * 64 + x * 32;
        #pragma unroll
        for (int rd = 0; rd < 2; ++rd) {
            cp16(&lds[cb][x][0][(rd * 512 + wave * 64) * 8], srcA[rd] + koff);
            cp16(&lds[cb][x][1][(rd * 512 + wave * 64) * 8], srcB[rd] + koff);
        }
    };

    f32x4 acc[8][4] = {};

    stage(0, 0); stage(0, 1); stage(1, 0);
    asm volatile("s_waitcnt vmcnt(8)" ::: "memory");
    __builtin_amdgcn_s_barrier();

    #pragma unroll
    for (int t = 0; t < 16; ++t) {
        const int c = t & 1;
        #pragma unroll
        for (int x = 0; x < 2; ++x) {
            if (x == 0) { if (t < 15) stage(t + 1, 1); }
            else        { if (t < 14) stage(t + 2, 0); }

            bf16x8 af[8], bfv[4];
            const u16* Ar = &lds[c][x][0][0];
            const u16* Br = &lds[c][x][1][0];
            #pragma unroll
            for (int mi = 0; mi < 8; ++mi) af[mi] = *(const bf16x8*)&Ar[offA[mi]];
            #pragma unroll
            for (int nj = 0; nj < 4; ++nj) bfv[nj] = *(const bf16x8*)&Br[offB[nj]];

            if (x == 0) {
                if (t < 15) asm volatile("s_waitcnt vmcnt(8)" ::: "memory");
                else        asm volatile("s_waitcnt vmcnt(0)" ::: "memory");
            } else {
                if (t < 14)       asm volatile("s_waitcnt vmcnt(8)" ::: "memory");
                else if (t == 14) asm volatile("s_waitcnt vmcnt(4)" ::: "memory");
            }
            __builtin_amdgcn_s_barrier();

            __builtin_amdgcn_s_setprio(1);
            #pragma unroll
            for (int mi = 0; mi < 8; ++mi)
                #pragma unroll
                for (int nj = 0; nj < 4; ++nj)
                    acc[mi][nj] = __builtin_amdgcn_mfma_f32_16x16x32_bf16(
                        af[mi], bfv[nj], acc[mi][nj], 0, 0, 0);
            __builtin_amdgcn_s_setprio(0);
            __builtin_amdgcn_s_barrier();
        }
    }

    const int hh = (n0 >> 6) + wc;
    if (z < 2) {
        u16* C = (z == 0) ? Qbf : Kbf;
        // z=0: fold 1/sqrt(64) AND log2(e) into Q so attn uses exp2 directly
        const float scale = (z == 0) ? 0.18033688f : 1.0f;
        #pragma unroll
        for (int mi = 0; mi < 8; ++mi) {
            const int mbase = m0 + wr * 128 + mi * 16 + quad * 4;
            const int bb = mbase >> 10, sb = mbase & 1023;
            #pragma unroll
            for (int nj = 0; nj < 4; ++nj) {
                const int dh = nj * 16 + ln;
                #pragma unroll
                for (int r = 0; r < 4; ++r)
                    C[(((size_t)bb * HH + hh) * SS + sb + r) * DHH + dh] =
                        f2bf(acc[mi][nj][r] * scale);
            }
        }
    } else {
        #pragma unroll
        for (int mi = 0; mi < 8; ++mi) {
            const int mbase = m0 + wr * 128 + mi * 16 + quad * 4;
            const int bb = mbase >> 10, sb = mbase & 1023;
            #pragma unroll
            for (int nj = 0; nj < 4; ++nj) {
                const int dh = nj * 16 + ln;
                uint2 pk;
                pk.x = cvt_pk_bf16(acc[mi][nj][0], acc[mi][nj][1]);
                pk.y = cvt_pk_bf16(acc[mi][nj][2], acc[mi][nj][3]);
                *(uint2*)&Vtb[(((size_t)bb * HH + hh) * DHH + dh) * SS + sb] = pk;
            }
        }
    }
}

// ---------------------------------------------------------------------------
// Flash attention. 8 waves (512 thr), QBLK=128 (16 q-rows/wave), KVBLK=64.
// Grid = 512 blocks = exactly 2 blocks/CU, one round; 16 waves/CU.
// K/V double-buffered, counted vmcnt(2) (never 0 mid-loop), raw s_barrier.
// Swapped QK^T (mfma(K,Q)) -> lane-local P row segment, cvt_pk + ds_write_b64.
// Q direct global->reg. kmask staged once as floats. LDS 53KB.
// ---------------------------------------------------------------------------
__global__ __launch_bounds__(512) void attn_mfma(const u16* __restrict__ Qg,
                                                 const u16* __restrict__ Kg,
                                                 const u16* __restrict__ Vtg,
                                                 const int* __restrict__ qmask,
                                                 const int* __restrict__ kmask,
                                                 float* __restrict__ O) {
    __shared__ u16 Ps[128 * 68];         // P spill, pitch 68 (b64-aligned rows)
    __shared__ u16 Ks[2][64 * 64];       // [key][dh] swizzled chunks, dbuf
    __shared__ u16 Vs[2][64 * 64];       // [dh][key] swizzled chunks, dbuf
    __shared__ float kmLds[SS];          // key-mask as float 0/1

    const int bid  = blockIdx.x;
    const int xcd  = bid & 7;
    const int rest = bid >> 3;               // 0..63
    const int bh   = (rest & 7) * 8 + xcd;   // 0..63, bh%8==xcd
    const int qt   = rest >> 3;              // 0..7
    const int b    = bh >> 4, h = bh & 15;
    const int q0   = qt * 128;
    const int tid  = threadIdx.x;
    const int wave = tid >> 6, lane = tid & 63;
    const int ln = lane & 15, quad = lane >> 4;
    const size_t bhs = (size_t)b * HH + h;

    // staging: 512 threads x 16B = 8KB = one full 64x64 bf16 tile each for K,V
    const int sr = tid >> 3, scsrc = (tid & 7) ^ ((tid >> 3) & 7);
    const u16* kSrc = &Kg[(bhs * SS + sr) * DHH + scsrc * 8];          // + t*64 rows
    const u16* vSrc = &Vtg[(bhs * DHH + sr) * SS + scsrc * 8];         // + t*64 cols
    auto stageKV = [&](int t) {
        const int cb = t & 1;
        cp16(&Ks[cb][wave * 512], kSrc + (size_t)t * 64 * DHH);
        cp16(&Vs[cb][wave * 512], vSrc + t * 64);
    };

    // --- prologue ---
    // Q fragment direct to registers: row q0+wave*16+ln, d = kk*32 + quad*8
    const u16* qrow = &Qg[(bhs * SS + q0 + wave * 16 + ln) * DHH];
    const bf16x8 qf0 = *(const bf16x8*)&qrow[quad * 8];
    const bf16x8 qf1 = *(const bf16x8*)&qrow[32 + quad * 8];
    asm volatile("" ::: "memory");       // pin qf issue before staging
    if (wave < 4)
        cp16(&kmLds[wave * 256], &kmask[b * SS + (wave * 64 + lane) * 4]);
    stageKV(0);
    stageKV(1);
    asm volatile("s_waitcnt vmcnt(2)" ::: "memory");   // qf+km+tile0 landed
    __builtin_amdgcn_s_barrier();

    // kmask int -> float in place (each thread owns 2)
    {
        const int2 iv = *(const int2*)&kmLds[tid * 2];
        float2 fv; fv.x = (float)iv.x; fv.y = (float)iv.y;
        *(float2*)&kmLds[tid * 2] = fv;
    }
    asm volatile("s_waitcnt lgkmcnt(0)" ::: "memory");
    __builtin_amdgcn_s_barrier();

    // hoisted swizzled LDS element offsets: row nt*16+ln, chunk kk*4+quad
    int off[4][2];
    #pragma unroll
    for (int nt = 0; nt < 4; ++nt) {
        const int r = nt * 16 + ln;
        off[nt][0] = ((r << 3) + ((0 + quad) ^ (r & 7))) << 3;
        off[nt][1] = ((r << 3) + ((4 + quad) ^ (r & 7))) << 3;
    }

    f32x4 o[4] = {};
    float lsum = 0.f;
    const f32x4 zero = {0.f, 0.f, 0.f, 0.f};
    const int prow = (wave * 16 + ln) * 68;   // this lane's Ps row base

    #pragma unroll 2
    for (int kt = 0; kt < SS / 64; ++kt) {
        const int cb = kt & 1;
        const u16* Kc = Ks[cb];
        const u16* Vc = Vs[cb];

        // S^T = K @ Q^T (Q pre-scaled by 0.125*log2e); p = fm * exp2(s)
        // out: k-row = nt*16 + quad*4 + r, q-col = wave*16 + ln
        #pragma unroll
        for (int nt = 0; nt < 4; ++nt) {
            const bf16x8 k0f = *(const bf16x8*)&Kc[off[nt][0]];
            const bf16x8 k1f = *(const bf16x8*)&Kc[off[nt][1]];
            f32x4 sacc = __builtin_amdgcn_mfma_f32_16x16x32_bf16(k0f, qf0, zero, 0, 0, 0);
            sacc = __builtin_amdgcn_mfma_f32_16x16x32_bf16(k1f, qf1, sacc, 0, 0, 0);
            const float4 fm = *(const float4*)&kmLds[kt * 64 + nt * 16 + quad * 4];
            const float p0 = fm.x * __builtin_amdgcn_exp2f(sacc[0]);
            const float p1 = fm.y * __builtin_amdgcn_exp2f(sacc[1]);
            const float p2 = fm.z * __builtin_amdgcn_exp2f(sacc[2]);
            const float p3 = fm.w * __builtin_amdgcn_exp2f(sacc[3]);
            lsum += (p0 + p1) + (p2 + p3);
            uint2 pk;
            pk.x = cvt_pk_bf16(p0, p1);
            pk.y = cvt_pk_bf16(p2, p3);
            *(uint2*)&Ps[prow + nt * 16 + quad * 4] = pk;   // 4 consecutive cols
        }
        // Ps rows are wave-private; same-wave lgkm ordering covers the RAW.

        // O += P @ V
        __builtin_amdgcn_s_setprio(1);
        #pragma unroll
        for (int kk2 = 0; kk2 < 2; ++kk2) {
            const bf16x8 pf = *(const bf16x8*)&Ps[prow + kk2 * 32 + quad * 8];
            #pragma unroll
            for (int nt2 = 0; nt2 < 4; ++nt2) {
                const bf16x8 vf = *(const bf16x8*)&Vc[off[nt2][kk2]];
                o[nt2] = __builtin_amdgcn_mfma_f32_16x16x32_bf16(pf, vf, o[nt2], 0, 0, 0);
            }
        }
        __builtin_amdgcn_s_setprio(0);

        if (kt == SS / 64 - 1) break;
        __builtin_amdgcn_s_barrier();        // all waves done reading buf cb
        if (kt + 2 < SS / 64) {
            stageKV(kt + 2);                 // overwrite buf cb
            asm volatile("s_waitcnt vmcnt(2)" ::: "memory");   // tile kt+1 landed
        } else {
            asm volatile("s_waitcnt vmcnt(0)" ::: "memory");   // last stage drain
        }
        __builtin_amdgcn_s_barrier();
    }

    // epilogue: quad-reduce lane-local l (q = wave*16+ln), normalize, store
    lsum += __shfl_xor(lsum, 16);
    lsum += __shfl_xor(lsum, 32);
    #pragma unroll
    for (int r = 0; r < 4; ++r) {
        const int qloc = quad * 4 + r;
        const float l = __shfl(lsum, qloc);        // lane qloc holds full sum
        const int q = q0 + wave * 16 + qloc;
        const float scale = (float)qmask[b * SS + q] / l;
        #pragma unroll
        for (int nt2 = 0; nt2 < 4; ++nt2)
            O[((size_t)b * SS + q) * DD + h * DHH + nt2 * 16 + ln] = o[nt2][r] * scale;
    }
}

// ---------------------------------------------------------------------------
// residual + LayerNorm over D=1024. One block (256 thr) per (b,s) row.
// ---------------------------------------------------------------------------
__global__ __launch_bounds__(256) void ln_kernel(const float* __restrict__ Qin,
                                                 const float* __restrict__ attn,
                                                 const float* __restrict__ gamma,
                                                 const float* __restrict__ beta,
                                                 float* __restrict__ out) {
    const int row = blockIdx.x;
    const int tid = threadIdx.x;
    const int wid = tid >> 6, lane = tid & 63;
    __shared__ float sred[4];

    const float4 qv = ((const float4*)Qin)[(size_t)row * 256 + tid];
    const float4 av = ((const float4*)attn)[(size_t)row * 256 + tid];
    float4 v;
    v.x = qv.x + av.x; v.y = qv.y + av.y;
    v.z = qv.z + av.z; v.w = qv.w + av.w;

    float sum = v.x + v.y + v.z + v.w;
    #pragma unroll
    for (int off = 32; off; off >>= 1) sum += __shfl_down(sum, off);
    if (lane == 0) sred[wid] = sum;
    __syncthreads();
    const float mean = (sred[0] + sred[1] + sred[2] + sred[3]) * (1.0f / DD);
    __syncthreads();

    const float dx = v.x - mean, dy = v.y - mean, dz = v.z - mean, dw = v.w - mean;
    float vs = dx * dx + dy * dy + dz * dz + dw * dw;
    #pragma unroll
    for (int off = 32; off; off >>= 1) vs += __shfl_down(vs, off);
    if (lane == 0) sred[wid] = vs;
    __syncthreads();
    const float var = (sred[0] + sred[1] + sred[2] + sred[3]) * (1.0f / DD);
    const float inv = rsqrtf(var + LN_EPS);

    const float4 g = ((const float4*)gamma)[tid];
    const float4 bt = ((const float4*)beta)[tid];
    float4 ov;
    ov.x = g.x * dx * inv + bt.x; ov.y = g.y * dy * inv + bt.y;
    ov.z = g.z * dz * inv + bt.z; ov.w = g.w * dw * inv + bt.w;
    ((float4*)out)[(size_t)row * 256 + tid] = ov;
}

// ---------------------------------------------------------------------------
extern "C" void kernel_launch(void* const* d_in, const int* in_sizes, int n_in,
                              void* d_out, int out_size, void* d_ws, size_t ws_size,
                              hipStream_t stream) {
    const float* queries = (const float*)d_in[0];
    const float* keys    = (const float*)d_in[1];
    const float* values  = (const float*)d_in[2];
    const int*   qmask   = (const int*)d_in[3];
    const int*   kmask   = (const int*)d_in[4];
    const float* Wq      = (const float*)d_in[5];
    const float* Wk      = (const float*)d_in[6];
    const float* Wv      = (const float*)d_in[7];
    const float* gamma   = (const float*)d_in[8];
    const float* beta    = (const float*)d_in[9];
    float* out = (float*)d_out;

    const size_t NTOK = (size_t)BB * SS;          // 4096
    // layout (54 MB): Abf[3] 24MB (Ob 16MB ALIASES it — gemm finishes reading
    // Abf before attn writes Ob; stream-ordered) | Qbf 8 | Kbf 8 | Vtb 8 | Wt 6
    u16* Abf = (u16*)d_ws;
    float* Ob = (float*)d_ws;
    u16* Qbf = Abf + 3 * NTOK * DD;
    u16* Kbf = Qbf + NTOK * DD;
    u16* Vtb = Kbf + NTOK * DD;
    u16* WtA = Vtb + NTOK * DD;

    prep<<<dim3(256, 1, 6), 256, 0, stream>>>(queries, keys, values, Wq, Wk, Wv, Abf, WtA);

    gemm_fused<<<192, 512, 0, stream>>>(Abf, WtA, Qbf, Kbf, Vtb);

    attn_mfma<<<BB * HH * (SS / 128), 512, 0, stream>>>(Qbf, Kbf, Vtb, qmask, kmask, Ob);

    ln_kernel<<<BB * SS, 256, 0, stream>>>(queries, Ob, gamma, beta, out);
}

// Round 4
// 185.230 us; speedup vs baseline: 1.1170x; 1.0088x over previous
//
#include <hip/hip_runtime.h>

#define BB   4
#define SS   1024
#define DD   1024
#define HH   16
#define DHH  64
#define LN_EPS  (1e-3f)

typedef unsigned short u16;
typedef __attribute__((ext_vector_type(8))) short bf16x8;
typedef __attribute__((ext_vector_type(4))) float f32x4;

__device__ __forceinline__ u16 f2bf(float f) {
    union { float f; unsigned int u; } v; v.f = f;
    return (u16)((v.u + 0x7FFFu + ((v.u >> 16) & 1u)) >> 16);
}

// pack two f32 -> two bf16 (RNE) in one VALU op
__device__ __forceinline__ unsigned int cvt_pk_bf16(float lo, float hi) {
    unsigned int r;
    asm("v_cvt_pk_bf16_f32 %0, %1, %2" : "=v"(r) : "v"(lo), "v"(hi));
    return r;
}

// async global->LDS, 16B per lane; lane i lands at lds + i*16 (wave-uniform
// base, no per-lane scatter — swizzle is applied to the SOURCE address).
__device__ __forceinline__ void cp16(void* lds, const void* g) {
    __builtin_amdgcn_global_load_lds(
        (const __attribute__((address_space(1))) unsigned int*)g,
        (__attribute__((address_space(3))) unsigned int*)lds, 16, 0, 0);
}

// ---------------------------------------------------------------------------
// prep: z<3 -> fp32->bf16 convert of queries/keys/values into Abf[3][4096][1024]
//       z>=3 -> W[k][n] fp32 -> Wt[n][k] bf16 (transpose+convert)
// ---------------------------------------------------------------------------
__global__ __launch_bounds__(256) void prep(const float* __restrict__ q,
                                            const float* __restrict__ k,
                                            const float* __restrict__ v,
                                            const float* __restrict__ Wq,
                                            const float* __restrict__ Wk,
                                            const float* __restrict__ Wv,
                                            u16* __restrict__ Abf,
                                            u16* __restrict__ WtA) {
    __shared__ float Ts[64][65];
    const int z = blockIdx.z;
    const int tid = threadIdx.x;
    if (z < 3) {
        const float* src = (z == 0) ? q : (z == 1) ? k : v;
        u16* dst = Abf + (size_t)z * ((size_t)BB * SS * DD);
        const int N8 = BB * SS * DD / 8;
        for (int i = blockIdx.x * 256 + tid; i < N8; i += 256 * 256) {
            const float4 f0 = ((const float4*)src)[i * 2];
            const float4 f1 = ((const float4*)src)[i * 2 + 1];
            union { u16 u[8]; uint4 o; } t;
            t.u[0] = f2bf(f0.x); t.u[1] = f2bf(f0.y);
            t.u[2] = f2bf(f0.z); t.u[3] = f2bf(f0.w);
            t.u[4] = f2bf(f1.x); t.u[5] = f2bf(f1.y);
            t.u[6] = f2bf(f1.z); t.u[7] = f2bf(f1.w);
            ((uint4*)dst)[i] = t.o;
        }
    } else {
        const float* W = (z == 3) ? Wq : (z == 4) ? Wk : Wv;
        u16* Wt = WtA + (size_t)(z - 3) * DD * DD;
        const int k0 = (blockIdx.x >> 4) * 64, n0 = (blockIdx.x & 15) * 64;
        #pragma unroll
        for (int it = 0; it < 4; ++it) {
            const int idx = tid + it * 256;
            const int r = idx >> 4, c4 = (idx & 15) * 4;
            const float4 vv = *(const float4*)&W[(size_t)(k0 + r) * DD + n0 + c4];
            Ts[r][c4 + 0] = vv.x; Ts[r][c4 + 1] = vv.y;
            Ts[r][c4 + 2] = vv.z; Ts[r][c4 + 3] = vv.w;
        }
        __syncthreads();
        const int n = tid >> 2, kc = (tid & 3) * 16;
        #pragma unroll
        for (int p = 0; p < 8; ++p) {
            const unsigned int lo = f2bf(Ts[kc + p * 2 + 0][n]);
            const unsigned int hi = f2bf(Ts[kc + p * 2 + 1][n]);
            *(unsigned int*)&Wt[(size_t)(n0 + n) * DD + k0 + kc + p * 2] = lo | (hi << 16);
        }
    }
}

// ---------------------------------------------------------------------------
// Fused QKV projection GEMM — 128x128 tile, BK=64, 4 waves (2x2), 256 thr.
// Double-buffered LDS (64 KB -> 2 blocks/CU co-residency), counted vmcnt(8)
// prefetch (never drains to 0 mid-loop), raw s_barrier. Grid = 768 blocks
// (3z x 32m x 8n) -> full machine, cross-block overlap hides stage waits.
//   z=0: Q*(0.125*log2e) [b][h][s][dh] (exp2-domain); z=1: K; z=2: V^T.
// ---------------------------------------------------------------------------
__global__ __launch_bounds__(256) void gemm_fused(const u16* __restrict__ Abf,
                                                  const u16* __restrict__ WtA,
                                                  u16* __restrict__ Qbf,
                                                  u16* __restrict__ Kbf,
                                                  u16* __restrict__ Vtb) {
    __shared__ u16 As[2][128 * 64];   // 16 KB per buf, XOR-swizzled chunks
    __shared__ u16 Bs[2][128 * 64];

    const int bid = blockIdx.x;
    const int swz = (bid & 7) * 96 + (bid >> 3);   // bijective, 768 % 8 == 0
    const int z   = swz >> 8;                      // 256 tiles per z
    const int rem = swz & 255;
    const int m0  = (rem >> 3) * 128;              // m-major within XCD: B panels reused
    const int n0  = (rem & 7) * 128;

    const u16* A  = Abf + (size_t)z * ((size_t)BB * SS * DD);
    const u16* Bm = WtA + (size_t)z * (DD * DD);

    const int tid  = threadIdx.x;
    const int wave = tid >> 6, lane = tid & 63;
    const int ln = lane & 15, quad = lane >> 4;
    const int mw = (wave & 1) * 64, nw = (wave >> 1) * 64;

    // staging decomposition: slot l = w*256+tid; row r = l>>3, stored chunk
    // cs = l&7 holds global chunk c = cs ^ (r&7)  (row = 8 x 16B chunks)
    const u16* srcA[4];
    const u16* srcB[4];
    #pragma unroll
    for (int w = 0; w < 4; ++w) {
        const int l = w * 256 + tid;
        const int r = l >> 3, cs = l & 7;
        const int c = cs ^ (r & 7);
        srcA[w] = A  + (size_t)(m0 + r) * DD + c * 8;
        srcB[w] = Bm + (size_t)(n0 + r) * DD + c * 8;
    }

    auto stage = [&](int T) {
        const int cb = T & 1;
        const int koff = T * 64;
        #pragma unroll
        for (int w = 0; w < 4; ++w)
            cp16(&As[cb][(w * 256 + wave * 64) * 8], srcA[w] + koff);
        #pragma unroll
        for (int w = 0; w < 4; ++w)
            cp16(&Bs[cb][(w * 256 + wave * 64) * 8], srcB[w] + koff);
    };

    f32x4 acc[4][4] = {};

    stage(0);
    #pragma unroll
    for (int t = 0; t < 16; ++t) {
        const int cb = t & 1;
        if (t < 15) stage(t + 1);                  // prefetch into other buf
        if (t < 15) asm volatile("s_waitcnt vmcnt(8)" ::: "memory");  // tile t landed
        else        asm volatile("s_waitcnt vmcnt(0)" ::: "memory");
        __builtin_amdgcn_s_barrier();

        #pragma unroll
        for (int kk = 0; kk < 2; ++kk) {
            bf16x8 af[4], bfv[4];
            #pragma unroll
            for (int i = 0; i < 4; ++i) {
                const int r = mw + i * 16 + ln;
                af[i] = *(const bf16x8*)&As[cb][((r << 3) + ((kk * 4 + quad) ^ (r & 7))) << 3];
            }
            #pragma unroll
            for (int j = 0; j < 4; ++j) {
                const int r = nw + j * 16 + ln;
                bfv[j] = *(const bf16x8*)&Bs[cb][((r << 3) + ((kk * 4 + quad) ^ (r & 7))) << 3];
            }
            __builtin_amdgcn_s_setprio(1);
            #pragma unroll
            for (int i = 0; i < 4; ++i)
                #pragma unroll
                for (int j = 0; j < 4; ++j)
                    acc[i][j] = __builtin_amdgcn_mfma_f32_16x16x32_bf16(af[i], bfv[j], acc[i][j], 0, 0, 0);
            __builtin_amdgcn_s_setprio(0);
        }
        __builtin_amdgcn_s_barrier();              // reads done before restage of cb
    }

    if (z < 2) {
        u16* C = (z == 0) ? Qbf : Kbf;
        // z=0: fold 1/sqrt(64) AND log2(e) into Q so attn uses exp2 directly
        const float scale = (z == 0) ? 0.18033688f : 1.0f;
        #pragma unroll
        for (int i = 0; i < 4; ++i) {
            const int mbase = m0 + mw + i * 16 + quad * 4;
            const int bb = mbase >> 10, sb = mbase & 1023;
            #pragma unroll
            for (int j = 0; j < 4; ++j) {
                const int n = n0 + nw + j * 16 + ln;
                const int hh = n >> 6, dh = n & 63;
                #pragma unroll
                for (int r = 0; r < 4; ++r)
                    C[(((size_t)bb * HH + hh) * SS + sb + r) * DHH + dh] =
                        f2bf(acc[i][j][r] * scale);
            }
        }
    } else {
        #pragma unroll
        for (int i = 0; i < 4; ++i) {
            const int mbase = m0 + mw + i * 16 + quad * 4;
            const int bb = mbase >> 10, sb = mbase & 1023;
            #pragma unroll
            for (int j = 0; j < 4; ++j) {
                const int n = n0 + nw + j * 16 + ln;
                const int hh = n >> 6, dh = n & 63;
                uint2 pk;
                pk.x = cvt_pk_bf16(acc[i][j][0], acc[i][j][1]);
                pk.y = cvt_pk_bf16(acc[i][j][2], acc[i][j][3]);
                *(uint2*)&Vtb[(((size_t)bb * HH + hh) * DHH + dh) * SS + sb] = pk;
            }
        }
    }
}

// ---------------------------------------------------------------------------
// Flash attention. 8 waves (512 thr), QBLK=128 (16 q-rows/wave), KVBLK=64.
// Grid = 512 blocks = exactly 2 blocks/CU, one round; 16 waves/CU.
// K/V double-buffered, counted vmcnt(2) (never 0 mid-loop), raw s_barrier.
// Swapped QK^T (mfma(K,Q)) -> lane-local P row segment, cvt_pk + ds_write_b64.
// Q direct global->reg. kmask staged once as floats. LDS 53KB.
// ---------------------------------------------------------------------------
__global__ __launch_bounds__(512) void attn_mfma(const u16* __restrict__ Qg,
                                                 const u16* __restrict__ Kg,
                                                 const u16* __restrict__ Vtg,
                                                 const int* __restrict__ qmask,
                                                 const int* __restrict__ kmask,
                                                 float* __restrict__ O) {
    __shared__ u16 Ps[128 * 68];         // P spill, pitch 68 (b64-aligned rows)
    __shared__ u16 Ks[2][64 * 64];       // [key][dh] swizzled chunks, dbuf
    __shared__ u16 Vs[2][64 * 64];       // [dh][key] swizzled chunks, dbuf
    __shared__ float kmLds[SS];          // key-mask as float 0/1

    const int bid  = blockIdx.x;
    const int xcd  = bid & 7;
    const int rest = bid >> 3;               // 0..63
    const int bh   = (rest & 7) * 8 + xcd;   // 0..63, bh%8==xcd
    const int qt   = rest >> 3;              // 0..7
    const int b    = bh >> 4, h = bh & 15;
    const int q0   = qt * 128;
    const int tid  = threadIdx.x;
    const int wave = tid >> 6, lane = tid & 63;
    const int ln = lane & 15, quad = lane >> 4;
    const size_t bhs = (size_t)b * HH + h;

    // staging: 512 threads x 16B = 8KB = one full 64x64 bf16 tile each for K,V
    const int sr = tid >> 3, scsrc = (tid & 7) ^ ((tid >> 3) & 7);
    const u16* kSrc = &Kg[(bhs * SS + sr) * DHH + scsrc * 8];          // + t*64 rows
    const u16* vSrc = &Vtg[(bhs * DHH + sr) * SS + scsrc * 8];         // + t*64 cols
    auto stageKV = [&](int t) {
        const int cb = t & 1;
        cp16(&Ks[cb][wave * 512], kSrc + (size_t)t * 64 * DHH);
        cp16(&Vs[cb][wave * 512], vSrc + t * 64);
    };

    // --- prologue ---
    // Q fragment direct to registers: row q0+wave*16+ln, d = kk*32 + quad*8
    const u16* qrow = &Qg[(bhs * SS + q0 + wave * 16 + ln) * DHH];
    const bf16x8 qf0 = *(const bf16x8*)&qrow[quad * 8];
    const bf16x8 qf1 = *(const bf16x8*)&qrow[32 + quad * 8];
    asm volatile("" ::: "memory");       // pin qf issue before staging
    if (wave < 4)
        cp16(&kmLds[wave * 256], &kmask[b * SS + (wave * 64 + lane) * 4]);
    stageKV(0);
    stageKV(1);
    asm volatile("s_waitcnt vmcnt(2)" ::: "memory");   // qf+km+tile0 landed
    __builtin_amdgcn_s_barrier();

    // kmask int -> float in place (each thread owns 2)
    {
        const int2 iv = *(const int2*)&kmLds[tid * 2];
        float2 fv; fv.x = (float)iv.x; fv.y = (float)iv.y;
        *(float2*)&kmLds[tid * 2] = fv;
    }
    asm volatile("s_waitcnt lgkmcnt(0)" ::: "memory");
    __builtin_amdgcn_s_barrier();

    // hoisted swizzled LDS element offsets: row nt*16+ln, chunk kk*4+quad
    int off[4][2];
    #pragma unroll
    for (int nt = 0; nt < 4; ++nt) {
        const int r = nt * 16 + ln;
        off[nt][0] = ((r << 3) + ((0 + quad) ^ (r & 7))) << 3;
        off[nt][1] = ((r << 3) + ((4 + quad) ^ (r & 7))) << 3;
    }

    f32x4 o[4] = {};
    float lsum = 0.f;
    const f32x4 zero = {0.f, 0.f, 0.f, 0.f};
    const int prow = (wave * 16 + ln) * 68;   // this lane's Ps row base

    #pragma unroll 2
    for (int kt = 0; kt < SS / 64; ++kt) {
        const int cb = kt & 1;
        const u16* Kc = Ks[cb];
        const u16* Vc = Vs[cb];

        // S^T = K @ Q^T (Q pre-scaled by 0.125*log2e); p = fm * exp2(s)
        // out: k-row = nt*16 + quad*4 + r, q-col = wave*16 + ln
        #pragma unroll
        for (int nt = 0; nt < 4; ++nt) {
            const bf16x8 k0f = *(const bf16x8*)&Kc[off[nt][0]];
            const bf16x8 k1f = *(const bf16x8*)&Kc[off[nt][1]];
            f32x4 sacc = __builtin_amdgcn_mfma_f32_16x16x32_bf16(k0f, qf0, zero, 0, 0, 0);
            sacc = __builtin_amdgcn_mfma_f32_16x16x32_bf16(k1f, qf1, sacc, 0, 0, 0);
            const float4 fm = *(const float4*)&kmLds[kt * 64 + nt * 16 + quad * 4];
            const float p0 = fm.x * __builtin_amdgcn_exp2f(sacc[0]);
            const float p1 = fm.y * __builtin_amdgcn_exp2f(sacc[1]);
            const float p2 = fm.z * __builtin_amdgcn_exp2f(sacc[2]);
            const float p3 = fm.w * __builtin_amdgcn_exp2f(sacc[3]);
            lsum += (p0 + p1) + (p2 + p3);
            uint2 pk;
            pk.x = cvt_pk_bf16(p0, p1);
            pk.y = cvt_pk_bf16(p2, p3);
            *(uint2*)&Ps[prow + nt * 16 + quad * 4] = pk;   // 4 consecutive cols
        }
        // Ps rows are wave-private; same-wave lgkm ordering covers the RAW.

        // O += P @ V
        __builtin_amdgcn_s_setprio(1);
        #pragma unroll
        for (int kk2 = 0; kk2 < 2; ++kk2) {
            const bf16x8 pf = *(const bf16x8*)&Ps[prow + kk2 * 32 + quad * 8];
            #pragma unroll
            for (int nt2 = 0; nt2 < 4; ++nt2) {
                const bf16x8 vf = *(const bf16x8*)&Vc[off[nt2][kk2]];
                o[nt2] = __builtin_amdgcn_mfma_f32_16x16x32_bf16(pf, vf, o[nt2], 0, 0, 0);
            }
        }
        __builtin_amdgcn_s_setprio(0);

        if (kt == SS / 64 - 1) break;
        __builtin_amdgcn_s_barrier();        // all waves done reading buf cb
        if (kt + 2 < SS / 64) {
            stageKV(kt + 2);                 // overwrite buf cb
            asm volatile("s_waitcnt vmcnt(2)" ::: "memory");   // tile kt+1 landed
        } else {
            asm volatile("s_waitcnt vmcnt(0)" ::: "memory");   // last stage drain
        }
        __builtin_amdgcn_s_barrier();
    }

    // epilogue: quad-reduce lane-local l (q = wave*16+ln), normalize, store
    lsum += __shfl_xor(lsum, 16);
    lsum += __shfl_xor(lsum, 32);
    #pragma unroll
    for (int r = 0; r < 4; ++r) {
        const int qloc = quad * 4 + r;
        const float l = __shfl(lsum, qloc);        // lane qloc holds full sum
        const int q = q0 + wave * 16 + qloc;
        const float scale = (float)qmask[b * SS + q] / l;
        #pragma unroll
        for (int nt2 = 0; nt2 < 4; ++nt2)
            O[((size_t)b * SS + q) * DD + h * DHH + nt2 * 16 + ln] = o[nt2][r] * scale;
    }
}

// ---------------------------------------------------------------------------
// residual + LayerNorm over D=1024. One block (256 thr) per (b,s) row.
// ---------------------------------------------------------------------------
__global__ __launch_bounds__(256) void ln_kernel(const float* __restrict__ Qin,
                                                 const float* __restrict__ attn,
                                                 const float* __restrict__ gamma,
                                                 const float* __restrict__ beta,
                                                 float* __restrict__ out) {
    const int row = blockIdx.x;
    const int tid = threadIdx.x;
    const int wid = tid >> 6, lane = tid & 63;
    __shared__ float sred[4];

    const float4 qv = ((const float4*)Qin)[(size_t)row * 256 + tid];
    const float4 av = ((const float4*)attn)[(size_t)row * 256 + tid];
    float4 v;
    v.x = qv.x + av.x; v.y = qv.y + av.y;
    v.z = qv.z + av.z; v.w = qv.w + av.w;

    float sum = v.x + v.y + v.z + v.w;
    #pragma unroll
    for (int off = 32; off; off >>= 1) sum += __shfl_down(sum, off);
    if (lane == 0) sred[wid] = sum;
    __syncthreads();
    const float mean = (sred[0] + sred[1] + sred[2] + sred[3]) * (1.0f / DD);
    __syncthreads();

    const float dx = v.x - mean, dy = v.y - mean, dz = v.z - mean, dw = v.w - mean;
    float vs = dx * dx + dy * dy + dz * dz + dw * dw;
    #pragma unroll
    for (int off = 32; off; off >>= 1) vs += __shfl_down(vs, off);
    if (lane == 0) sred[wid] = vs;
    __syncthreads();
    const float var = (sred[0] + sred[1] + sred[2] + sred[3]) * (1.0f / DD);
    const float inv = rsqrtf(var + LN_EPS);

    const float4 g = ((const float4*)gamma)[tid];
    const float4 bt = ((const float4*)beta)[tid];
    float4 ov;
    ov.x = g.x * dx * inv + bt.x; ov.y = g.y * dy * inv + bt.y;
    ov.z = g.z * dz * inv + bt.z; ov.w = g.w * dw * inv + bt.w;
    ((float4*)out)[(size_t)row * 256 + tid] = ov;
}

// ---------------------------------------------------------------------------
extern "C" void kernel_launch(void* const* d_in, const int* in_sizes, int n_in,
                              void* d_out, int out_size, void* d_ws, size_t ws_size,
                              hipStream_t stream) {
    const float* queries = (const float*)d_in[0];
    const float* keys    = (const float*)d_in[1];
    const float* values  = (const float*)d_in[2];
    const int*   qmask   = (const int*)d_in[3];
    const int*   kmask   = (const int*)d_in[4];
    const float* Wq      = (const float*)d_in[5];
    const float* Wk      = (const float*)d_in[6];
    const float* Wv      = (const float*)d_in[7];
    const float* gamma   = (const float*)d_in[8];
    const float* beta    = (const float*)d_in[9];
    float* out = (float*)d_out;

    const size_t NTOK = (size_t)BB * SS;          // 4096
    // layout (54 MB): Abf[3] 24MB (Ob 16MB ALIASES it — gemm finishes reading
    // Abf before attn writes Ob; stream-ordered) | Qbf 8 | Kbf 8 | Vtb 8 | Wt 6
    u16* Abf = (u16*)d_ws;
    float* Ob = (float*)d_ws;
    u16* Qbf = Abf + 3 * NTOK * DD;
    u16* Kbf = Qbf + NTOK * DD;
    u16* Vtb = Kbf + NTOK * DD;
    u16* WtA = Vtb + NTOK * DD;

    prep<<<dim3(256, 1, 6), 256, 0, stream>>>(queries, keys, values, Wq, Wk, Wv, Abf, WtA);

    gemm_fused<<<768, 256, 0, stream>>>(Abf, WtA, Qbf, Kbf, Vtb);

    attn_mfma<<<BB * HH * (SS / 128), 512, 0, stream>>>(Qbf, Kbf, Vtb, qmask, kmask, Ob);

    ln_kernel<<<BB * SS, 256, 0, stream>>>(queries, Ob, gamma, beta, out);
}

// Round 5
// 179.082 us; speedup vs baseline: 1.1554x; 1.0343x over previous
//
#include <hip/hip_runtime.h>

#define BB   4
#define SS   1024
#define DD   1024
#define HH   16
#define DHH  64
#define LN_EPS  (1e-3f)

typedef unsigned short u16;
typedef __attribute__((ext_vector_type(8))) short bf16x8;
typedef __attribute__((ext_vector_type(4))) float f32x4;

__device__ __forceinline__ u16 f2bf(float f) {
    union { float f; unsigned int u; } v; v.f = f;
    return (u16)((v.u + 0x7FFFu + ((v.u >> 16) & 1u)) >> 16);
}

// pack two f32 -> two bf16 (RNE) in one VALU op
__device__ __forceinline__ unsigned int cvt_pk_bf16(float lo, float hi) {
    unsigned int r;
    asm("v_cvt_pk_bf16_f32 %0, %1, %2" : "=v"(r) : "v"(lo), "v"(hi));
    return r;
}

// async global->LDS, 16B per lane; lane i lands at lds + i*16 (wave-uniform
// base, no per-lane scatter — swizzle is applied to the SOURCE address).
__device__ __forceinline__ void cp16(void* lds, const void* g) {
    __builtin_amdgcn_global_load_lds(
        (const __attribute__((address_space(1))) unsigned int*)g,
        (__attribute__((address_space(3))) unsigned int*)lds, 16, 0, 0);
}

// ---------------------------------------------------------------------------
// prep: z<3 -> fp32->bf16 convert of queries/keys/values into Abf[3][4096][1024]
//       z>=3 -> W[k][n] fp32 -> Wt[n][k] bf16 (transpose+convert)
// ---------------------------------------------------------------------------
__global__ __launch_bounds__(256) void prep(const float* __restrict__ q,
                                            const float* __restrict__ k,
                                            const float* __restrict__ v,
                                            const float* __restrict__ Wq,
                                            const float* __restrict__ Wk,
                                            const float* __restrict__ Wv,
                                            u16* __restrict__ Abf,
                                            u16* __restrict__ WtA) {
    __shared__ float Ts[64][65];
    const int z = blockIdx.z;
    const int tid = threadIdx.x;
    if (z < 3) {
        const float* src = (z == 0) ? q : (z == 1) ? k : v;
        u16* dst = Abf + (size_t)z * ((size_t)BB * SS * DD);
        const int N8 = BB * SS * DD / 8;
        for (int i = blockIdx.x * 256 + tid; i < N8; i += 256 * 256) {
            const float4 f0 = ((const float4*)src)[i * 2];
            const float4 f1 = ((const float4*)src)[i * 2 + 1];
            union { u16 u[8]; uint4 o; } t;
            t.u[0] = f2bf(f0.x); t.u[1] = f2bf(f0.y);
            t.u[2] = f2bf(f0.z); t.u[3] = f2bf(f0.w);
            t.u[4] = f2bf(f1.x); t.u[5] = f2bf(f1.y);
            t.u[6] = f2bf(f1.z); t.u[7] = f2bf(f1.w);
            ((uint4*)dst)[i] = t.o;
        }
    } else {
        const float* W = (z == 3) ? Wq : (z == 4) ? Wk : Wv;
        u16* Wt = WtA + (size_t)(z - 3) * DD * DD;
        const int k0 = (blockIdx.x >> 4) * 64, n0 = (blockIdx.x & 15) * 64;
        #pragma unroll
        for (int it = 0; it < 4; ++it) {
            const int idx = tid + it * 256;
            const int r = idx >> 4, c4 = (idx & 15) * 4;
            const float4 vv = *(const float4*)&W[(size_t)(k0 + r) * DD + n0 + c4];
            Ts[r][c4 + 0] = vv.x; Ts[r][c4 + 1] = vv.y;
            Ts[r][c4 + 2] = vv.z; Ts[r][c4 + 3] = vv.w;
        }
        __syncthreads();
        const int n = tid >> 2, kc = (tid & 3) * 16;
        #pragma unroll
        for (int p = 0; p < 8; ++p) {
            const unsigned int lo = f2bf(Ts[kc + p * 2 + 0][n]);
            const unsigned int hi = f2bf(Ts[kc + p * 2 + 1][n]);
            *(unsigned int*)&Wt[(size_t)(n0 + n) * DD + k0 + kc + p * 2] = lo | (hi << 16);
        }
    }
}

// ---------------------------------------------------------------------------
// Fused QKV projection GEMM — 128x128 tile, BK=64, 4 waves (2x2), 256 thr.
// m97 structure: single-buffer LDS (32 KB), global_load_lds staging, 2
// barriers per K-step. __launch_bounds__(256,3) forces <=170 regs/wave ->
// 3 blocks/CU co-resident (12 waves/CU): cross-block overlap hides the
// barrier drain (m114). Staging srcs use 2 base ptrs + uniform w*32*DD
// offsets (chunk swizzle is w-invariant) to cut VGPR pressure.
// Grid = 768 blocks (3z x 32m x 8n), XCD-swizzled, = 3 clean rounds.
//   z=0: Q*(0.125*log2e) [b][h][s][dh] (exp2-domain); z=1: K; z=2: V^T.
// ---------------------------------------------------------------------------
__global__ __launch_bounds__(256, 3) void gemm_fused(const u16* __restrict__ Abf,
                                                     const u16* __restrict__ WtA,
                                                     u16* __restrict__ Qbf,
                                                     u16* __restrict__ Kbf,
                                                     u16* __restrict__ Vtb) {
    __shared__ u16 As[128 * 64];   // 16 KB, XOR-swizzled chunks
    __shared__ u16 Bs[128 * 64];

    const int bid = blockIdx.x;
    const int swz = (bid & 7) * 96 + (bid >> 3);   // bijective, 768 % 8 == 0
    const int z   = swz >> 8;                      // 256 tiles per z
    const int rem = swz & 255;
    const int m0  = (rem >> 3) * 128;              // m-major within XCD: B panels reused
    const int n0  = (rem & 7) * 128;

    const u16* A  = Abf + (size_t)z * ((size_t)BB * SS * DD);
    const u16* Bm = WtA + (size_t)z * (DD * DD);

    const int tid  = threadIdx.x;
    const int wave = tid >> 6, lane = tid & 63;
    const int ln = lane & 15, quad = lane >> 4;
    const int mw = (wave & 1) * 64, nw = (wave >> 1) * 64;

    // staging decomposition for slot l = w*256+tid: row r = w*32 + (tid>>3),
    // stored chunk cs = tid&7 holds global chunk c = cs ^ (r&7); r&7 and c
    // are w-invariant (w*32 % 8 == 0) -> single base + uniform w offset.
    const int r0 = tid >> 3;
    const int c0 = (tid & 7) ^ (r0 & 7);
    const u16* srcA0 = A  + (size_t)(m0 + r0) * DD + c0 * 8;
    const u16* srcB0 = Bm + (size_t)(n0 + r0) * DD + c0 * 8;

    f32x4 acc[4][4] = {};

    for (int t = 0; t < 16; ++t) {
        const int koff = t * 64;
        __syncthreads();
        #pragma unroll
        for (int w = 0; w < 4; ++w) {
            cp16(&As[(w * 256 + wave * 64) * 8], srcA0 + (size_t)w * 32 * DD + koff);
            cp16(&Bs[(w * 256 + wave * 64) * 8], srcB0 + (size_t)w * 32 * DD + koff);
        }
        __syncthreads();

        #pragma unroll
        for (int kk = 0; kk < 2; ++kk) {
            bf16x8 af[4], bfv[4];
            #pragma unroll
            for (int i = 0; i < 4; ++i) {
                const int r = mw + i * 16 + ln;
                af[i] = *(const bf16x8*)&As[((r << 3) + ((kk * 4 + quad) ^ (r & 7))) << 3];
            }
            #pragma unroll
            for (int j = 0; j < 4; ++j) {
                const int r = nw + j * 16 + ln;
                bfv[j] = *(const bf16x8*)&Bs[((r << 3) + ((kk * 4 + quad) ^ (r & 7))) << 3];
            }
            __builtin_amdgcn_s_setprio(1);
            #pragma unroll
            for (int i = 0; i < 4; ++i)
                #pragma unroll
                for (int j = 0; j < 4; ++j)
                    acc[i][j] = __builtin_amdgcn_mfma_f32_16x16x32_bf16(af[i], bfv[j], acc[i][j], 0, 0, 0);
            __builtin_amdgcn_s_setprio(0);
        }
    }

    if (z < 2) {
        u16* C = (z == 0) ? Qbf : Kbf;
        // z=0: fold 1/sqrt(64) AND log2(e) into Q so attn uses exp2 directly
        const float scale = (z == 0) ? 0.18033688f : 1.0f;
        #pragma unroll
        for (int i = 0; i < 4; ++i) {
            const int mbase = m0 + mw + i * 16 + quad * 4;
            const int bb = mbase >> 10, sb = mbase & 1023;
            #pragma unroll
            for (int j = 0; j < 4; ++j) {
                const int n = n0 + nw + j * 16 + ln;
                const int hh = n >> 6, dh = n & 63;
                #pragma unroll
                for (int r = 0; r < 4; ++r)
                    C[(((size_t)bb * HH + hh) * SS + sb + r) * DHH + dh] =
                        f2bf(acc[i][j][r] * scale);
            }
        }
    } else {
        #pragma unroll
        for (int i = 0; i < 4; ++i) {
            const int mbase = m0 + mw + i * 16 + quad * 4;
            const int bb = mbase >> 10, sb = mbase & 1023;
            #pragma unroll
            for (int j = 0; j < 4; ++j) {
                const int n = n0 + nw + j * 16 + ln;
                const int hh = n >> 6, dh = n & 63;
                uint2 pk;
                pk.x = cvt_pk_bf16(acc[i][j][0], acc[i][j][1]);
                pk.y = cvt_pk_bf16(acc[i][j][2], acc[i][j][3]);
                *(uint2*)&Vtb[(((size_t)bb * HH + hh) * DHH + dh) * SS + sb] = pk;
            }
        }
    }
}

// ---------------------------------------------------------------------------
// Flash attention. 8 waves (512 thr), QBLK=128 (16 q-rows/wave), KVBLK=64.
// Grid = 512 blocks = exactly 2 blocks/CU, one round; 16 waves/CU.
// K/V double-buffered, counted vmcnt(2) (never 0 mid-loop), raw s_barrier.
// Swapped QK^T (mfma(K,Q)) -> lane-local P row segment, cvt_pk + ds_write_b64.
// Q direct global->reg. kmask staged once as floats. LDS 53KB.
// ---------------------------------------------------------------------------
__global__ __launch_bounds__(512) void attn_mfma(const u16* __restrict__ Qg,
                                                 const u16* __restrict__ Kg,
                                                 const u16* __restrict__ Vtg,
                                                 const int* __restrict__ qmask,
                                                 const int* __restrict__ kmask,
                                                 float* __restrict__ O) {
    __shared__ u16 Ps[128 * 68];         // P spill, pitch 68 (b64-aligned rows)
    __shared__ u16 Ks[2][64 * 64];       // [key][dh] swizzled chunks, dbuf
    __shared__ u16 Vs[2][64 * 64];       // [dh][key] swizzled chunks, dbuf
    __shared__ float kmLds[SS];          // key-mask as float 0/1

    const int bid  = blockIdx.x;
    const int xcd  = bid & 7;
    const int rest = bid >> 3;               // 0..63
    const int bh   = (rest & 7) * 8 + xcd;   // 0..63, bh%8==xcd
    const int qt   = rest >> 3;              // 0..7
    const int b    = bh >> 4, h = bh & 15;
    const int q0   = qt * 128;
    const int tid  = threadIdx.x;
    const int wave = tid >> 6, lane = tid & 63;
    const int ln = lane & 15, quad = lane >> 4;
    const size_t bhs = (size_t)b * HH + h;

    // staging: 512 threads x 16B = 8KB = one full 64x64 bf16 tile each for K,V
    const int sr = tid >> 3, scsrc = (tid & 7) ^ ((tid >> 3) & 7);
    const u16* kSrc = &Kg[(bhs * SS + sr) * DHH + scsrc * 8];          // + t*64 rows
    const u16* vSrc = &Vtg[(bhs * DHH + sr) * SS + scsrc * 8];         // + t*64 cols
    auto stageKV = [&](int t) {
        const int cb = t & 1;
        cp16(&Ks[cb][wave * 512], kSrc + (size_t)t * 64 * DHH);
        cp16(&Vs[cb][wave * 512], vSrc + t * 64);
    };

    // --- prologue ---
    // Q fragment direct to registers: row q0+wave*16+ln, d = kk*32 + quad*8
    const u16* qrow = &Qg[(bhs * SS + q0 + wave * 16 + ln) * DHH];
    const bf16x8 qf0 = *(const bf16x8*)&qrow[quad * 8];
    const bf16x8 qf1 = *(const bf16x8*)&qrow[32 + quad * 8];
    asm volatile("" ::: "memory");       // pin qf issue before staging
    if (wave < 4)
        cp16(&kmLds[wave * 256], &kmask[b * SS + (wave * 64 + lane) * 4]);
    stageKV(0);
    stageKV(1);
    asm volatile("s_waitcnt vmcnt(2)" ::: "memory");   // qf+km+tile0 landed
    __builtin_amdgcn_s_barrier();

    // kmask int -> float in place (each thread owns 2)
    {
        const int2 iv = *(const int2*)&kmLds[tid * 2];
        float2 fv; fv.x = (float)iv.x; fv.y = (float)iv.y;
        *(float2*)&kmLds[tid * 2] = fv;
    }
    asm volatile("s_waitcnt lgkmcnt(0)" ::: "memory");
    __builtin_amdgcn_s_barrier();

    // hoisted swizzled LDS element offsets: row nt*16+ln, chunk kk*4+quad
    int off[4][2];
    #pragma unroll
    for (int nt = 0; nt < 4; ++nt) {
        const int r = nt * 16 + ln;
        off[nt][0] = ((r << 3) + ((0 + quad) ^ (r & 7))) << 3;
        off[nt][1] = ((r << 3) + ((4 + quad) ^ (r & 7))) << 3;
    }

    f32x4 o[4] = {};
    float lsum = 0.f;
    const f32x4 zero = {0.f, 0.f, 0.f, 0.f};
    const int prow = (wave * 16 + ln) * 68;   // this lane's Ps row base

    #pragma unroll 2
    for (int kt = 0; kt < SS / 64; ++kt) {
        const int cb = kt & 1;
        const u16* Kc = Ks[cb];
        const u16* Vc = Vs[cb];

        // S^T = K @ Q^T (Q pre-scaled by 0.125*log2e); p = fm * exp2(s)
        // out: k-row = nt*16 + quad*4 + r, q-col = wave*16 + ln
        #pragma unroll
        for (int nt = 0; nt < 4; ++nt) {
            const bf16x8 k0f = *(const bf16x8*)&Kc[off[nt][0]];
            const bf16x8 k1f = *(const bf16x8*)&Kc[off[nt][1]];
            f32x4 sacc = __builtin_amdgcn_mfma_f32_16x16x32_bf16(k0f, qf0, zero, 0, 0, 0);
            sacc = __builtin_amdgcn_mfma_f32_16x16x32_bf16(k1f, qf1, sacc, 0, 0, 0);
            const float4 fm = *(const float4*)&kmLds[kt * 64 + nt * 16 + quad * 4];
            const float p0 = fm.x * __builtin_amdgcn_exp2f(sacc[0]);
            const float p1 = fm.y * __builtin_amdgcn_exp2f(sacc[1]);
            const float p2 = fm.z * __builtin_amdgcn_exp2f(sacc[2]);
            const float p3 = fm.w * __builtin_amdgcn_exp2f(sacc[3]);
            lsum += (p0 + p1) + (p2 + p3);
            uint2 pk;
            pk.x = cvt_pk_bf16(p0, p1);
            pk.y = cvt_pk_bf16(p2, p3);
            *(uint2*)&Ps[prow + nt * 16 + quad * 4] = pk;   // 4 consecutive cols
        }
        // Ps rows are wave-private; same-wave lgkm ordering covers the RAW.

        // O += P @ V
        __builtin_amdgcn_s_setprio(1);
        #pragma unroll
        for (int kk2 = 0; kk2 < 2; ++kk2) {
            const bf16x8 pf = *(const bf16x8*)&Ps[prow + kk2 * 32 + quad * 8];
            #pragma unroll
            for (int nt2 = 0; nt2 < 4; ++nt2) {
                const bf16x8 vf = *(const bf16x8*)&Vc[off[nt2][kk2]];
                o[nt2] = __builtin_amdgcn_mfma_f32_16x16x32_bf16(pf, vf, o[nt2], 0, 0, 0);
            }
        }
        __builtin_amdgcn_s_setprio(0);

        if (kt == SS / 64 - 1) break;
        __builtin_amdgcn_s_barrier();        // all waves done reading buf cb
        if (kt + 2 < SS / 64) {
            stageKV(kt + 2);                 // overwrite buf cb
            asm volatile("s_waitcnt vmcnt(2)" ::: "memory");   // tile kt+1 landed
        } else {
            asm volatile("s_waitcnt vmcnt(0)" ::: "memory");   // last stage drain
        }
        __builtin_amdgcn_s_barrier();
    }

    // epilogue: quad-reduce lane-local l (q = wave*16+ln), normalize, store
    lsum += __shfl_xor(lsum, 16);
    lsum += __shfl_xor(lsum, 32);
    #pragma unroll
    for (int r = 0; r < 4; ++r) {
        const int qloc = quad * 4 + r;
        const float l = __shfl(lsum, qloc);        // lane qloc holds full sum
        const int q = q0 + wave * 16 + qloc;
        const float scale = (float)qmask[b * SS + q] / l;
        #pragma unroll
        for (int nt2 = 0; nt2 < 4; ++nt2)
            O[((size_t)b * SS + q) * DD + h * DHH + nt2 * 16 + ln] = o[nt2][r] * scale;
    }
}

// ---------------------------------------------------------------------------
// residual + LayerNorm over D=1024. One block (256 thr) per (b,s) row.
// ---------------------------------------------------------------------------
__global__ __launch_bounds__(256) void ln_kernel(const float* __restrict__ Qin,
                                                 const float* __restrict__ attn,
                                                 const float* __restrict__ gamma,
                                                 const float* __restrict__ beta,
                                                 float* __restrict__ out) {
    const int row = blockIdx.x;
    const int tid = threadIdx.x;
    const int wid = tid >> 6, lane = tid & 63;
    __shared__ float sred[4];

    const float4 qv = ((const float4*)Qin)[(size_t)row * 256 + tid];
    const float4 av = ((const float4*)attn)[(size_t)row * 256 + tid];
    float4 v;
    v.x = qv.x + av.x; v.y = qv.y + av.y;
    v.z = qv.z + av.z; v.w = qv.w + av.w;

    float sum = v.x + v.y + v.z + v.w;
    #pragma unroll
    for (int off = 32; off; off >>= 1) sum += __shfl_down(sum, off);
    if (lane == 0) sred[wid] = sum;
    __syncthreads();
    const float mean = (sred[0] + sred[1] + sred[2] + sred[3]) * (1.0f / DD);
    __syncthreads();

    const float dx = v.x - mean, dy = v.y - mean, dz = v.z - mean, dw = v.w - mean;
    float vs = dx * dx + dy * dy + dz * dz + dw * dw;
    #pragma unroll
    for (int off = 32; off; off >>= 1) vs += __shfl_down(vs, off);
    if (lane == 0) sred[wid] = vs;
    __syncthreads();
    const float var = (sred[0] + sred[1] + sred[2] + sred[3]) * (1.0f / DD);
    const float inv = rsqrtf(var + LN_EPS);

    const float4 g = ((const float4*)gamma)[tid];
    const float4 bt = ((const float4*)beta)[tid];
    float4 ov;
    ov.x = g.x * dx * inv + bt.x; ov.y = g.y * dy * inv + bt.y;
    ov.z = g.z * dz * inv + bt.z; ov.w = g.w * dw * inv + bt.w;
    ((float4*)out)[(size_t)row * 256 + tid] = ov;
}

// ---------------------------------------------------------------------------
extern "C" void kernel_launch(void* const* d_in, const int* in_sizes, int n_in,
                              void* d_out, int out_size, void* d_ws, size_t ws_size,
                              hipStream_t stream) {
    const float* queries = (const float*)d_in[0];
    const float* keys    = (const float*)d_in[1];
    const float* values  = (const float*)d_in[2];
    const int*   qmask   = (const int*)d_in[3];
    const int*   kmask   = (const int*)d_in[4];
    const float* Wq      = (const float*)d_in[5];
    const float* Wk      = (const float*)d_in[6];
    const float* Wv      = (const float*)d_in[7];
    const float* gamma   = (const float*)d_in[8];
    const float* beta    = (const float*)d_in[9];
    float* out = (float*)d_out;

    const size_t NTOK = (size_t)BB * SS;          // 4096
    // layout (54 MB): Abf[3] 24MB (Ob 16MB ALIASES it — gemm finishes reading
    // Abf before attn writes Ob; stream-ordered) | Qbf 8 | Kbf 8 | Vtb 8 | Wt 6
    u16* Abf = (u16*)d_ws;
    float* Ob = (float*)d_ws;
    u16* Qbf = Abf + 3 * NTOK * DD;
    u16* Kbf = Qbf + NTOK * DD;
    u16* Vtb = Kbf + NTOK * DD;
    u16* WtA = Vtb + NTOK * DD;

    prep<<<dim3(256, 1, 6), 256, 0, stream>>>(queries, keys, values, Wq, Wk, Wv, Abf, WtA);

    gemm_fused<<<768, 256, 0, stream>>>(Abf, WtA, Qbf, Kbf, Vtb);

    attn_mfma<<<BB * HH * (SS / 128), 512, 0, stream>>>(Qbf, Kbf, Vtb, qmask, kmask, Ob);

    ln_kernel<<<BB * SS, 256, 0, stream>>>(queries, Ob, gamma, beta, out);
}